// Round 1
// baseline (1823.055 us; speedup 1.0000x reference)
//
#include <hip/hip_runtime.h>
#include <cstdint>
#include <cstddef>

#define M_TOK 8192
#define DIMM  512
#define HEADS 8
#define DH    64
#define MLPD  2048
#define DEPTH 6

typedef unsigned short u16;
typedef unsigned int   u32;
typedef __attribute__((ext_vector_type(8))) short short8;   // 8 bf16 (4 VGPRs)
typedef __attribute__((ext_vector_type(4))) float f32x4;    // 4 fp32 acc

__device__ __forceinline__ float bf2f(u16 u){ return __uint_as_float(((u32)u) << 16); }
__device__ __forceinline__ u16 f2bf(float f){
    u32 x = __float_as_uint(f);
    u32 r = x + 0x7fffu + ((x >> 16) & 1u);   // RNE
    return (u16)(r >> 16);
}
// packed f32x2 -> bf16x2 (RNE), 1 instr for 2 converts (T12 primitive)
__device__ __forceinline__ u32 cvt_pk_bf16(float a, float b){
    u32 r;
    asm("v_cvt_pk_bf16_f32 %0, %1, %2" : "=v"(r) : "v"(a), "v"(b));
    return r;
}

// ---------------- weight transpose + cvt: fp32 in[R][C] -> bf16 out[C][R], z layers ----------------
__global__ void k_transpose_cvt(const float* __restrict__ in, u16* __restrict__ out, int R, int C){
    __shared__ u16 tile[32][33];
    size_t zoff = (size_t)blockIdx.z * R * C;
    in += zoff; out += zoff;
    int c0 = blockIdx.x * 32, r0 = blockIdx.y * 32;
    int tx = threadIdx.x, ty = threadIdx.y;           // (32, 8)
    #pragma unroll
    for (int i = 0; i < 32; i += 8)
        tile[ty + i][tx] = f2bf(in[(size_t)(r0 + ty + i) * C + c0 + tx]);
    __syncthreads();
    #pragma unroll
    for (int i = 0; i < 32; i += 8)
        out[(size_t)(c0 + ty + i) * R + r0 + tx] = tile[tx][ty + i];
}

// ---------------- LayerNorm: fp32 x row -> bf16 out; 4 rows/block, 1 wave/row ----------------
__global__ __launch_bounds__(256) void k_layernorm(const float* __restrict__ x,
                                                   const float* __restrict__ s,
                                                   const float* __restrict__ b,
                                                   u16* __restrict__ out){
    int row = blockIdx.x * 4 + (threadIdx.x >> 6);
    int lane = threadIdx.x & 63;
    const float* xp = x + (size_t)row * DIMM + lane * 8;
    float v[8];
    #pragma unroll
    for (int c = 0; c < 8; c++) v[c] = xp[c];
    float sum = 0.f, sq = 0.f;
    #pragma unroll
    for (int c = 0; c < 8; c++){ sum += v[c]; sq += v[c] * v[c]; }
    #pragma unroll
    for (int m = 32; m >= 1; m >>= 1){
        sum += __shfl_xor(sum, m);
        sq  += __shfl_xor(sq,  m);
    }
    float mu  = sum * (1.f / DIMM);
    float var = sq * (1.f / DIMM) - mu * mu;
    float rs  = rsqrtf(var + 1e-5f);
    u16* op = out + (size_t)row * DIMM + lane * 8;
    #pragma unroll
    for (int c = 0; c < 8; c++){
        int col = lane * 8 + c;
        op[c] = f2bf((v[c] - mu) * rs * s[col] + b[col]);
    }
}

__device__ __forceinline__ float gelu_exact(float v){
    return 0.5f * v * (1.f + erff(v * 0.70710678118654752f));
}

#define LDT64 72   // 64 k-elems + 8 pad; 144 B rows, 16B-aligned

// ---------------- 128x128-tile GEMM, BK=64, VGPR staging, coalesced LDS epilogue ----------------
// MODE 0: Cout=bf16(acc); MODE 1: Cout=bf16(gelu(acc+bias)).
template<int MODE>
__global__ __launch_bounds__(256) void k_gemm128b(const u16* __restrict__ A,
                                                  const u16* __restrict__ Bt,
                                                  const float* __restrict__ bias,
                                                  u16* __restrict__ Cout,
                                                  int M, int N, int K){
    __shared__ u16 As[128 * LDT64];
    __shared__ u16 Bs[128 * LDT64];
    int m0 = blockIdx.y * 128, n0 = blockIdx.x * 128;
    int t = threadIdx.x;
    int w = t >> 6, lane = t & 63;
    int mi = lane & 15, quad = lane >> 4;
    int wr = w >> 1, wc = w & 1;
    int srow = t >> 1, scol = (t & 1) * 32;          // 128 rows x 64 k / 256 thr

    const u16* ag = A  + (size_t)(m0 + srow) * K + scol;
    const u16* bg = Bt + (size_t)(n0 + srow) * K + scol;

    f32x4 acc[4][4];
    #pragma unroll
    for (int mt = 0; mt < 4; mt++)
        #pragma unroll
        for (int nt = 0; nt < 4; nt++) acc[mt][nt] = (f32x4){0.f, 0.f, 0.f, 0.f};

    for (int k0 = 0; k0 < K; k0 += 64){
        uint4 a0 = *(const uint4*)(ag + k0);
        uint4 a1 = *(const uint4*)(ag + k0 + 8);
        uint4 a2 = *(const uint4*)(ag + k0 + 16);
        uint4 a3 = *(const uint4*)(ag + k0 + 24);
        uint4 b0 = *(const uint4*)(bg + k0);
        uint4 b1 = *(const uint4*)(bg + k0 + 8);
        uint4 b2 = *(const uint4*)(bg + k0 + 16);
        uint4 b3 = *(const uint4*)(bg + k0 + 24);
        __syncthreads();
        *(uint4*)&As[srow * LDT64 + scol]      = a0;
        *(uint4*)&As[srow * LDT64 + scol + 8]  = a1;
        *(uint4*)&As[srow * LDT64 + scol + 16] = a2;
        *(uint4*)&As[srow * LDT64 + scol + 24] = a3;
        *(uint4*)&Bs[srow * LDT64 + scol]      = b0;
        *(uint4*)&Bs[srow * LDT64 + scol + 8]  = b1;
        *(uint4*)&Bs[srow * LDT64 + scol + 16] = b2;
        *(uint4*)&Bs[srow * LDT64 + scol + 24] = b3;
        __syncthreads();
        #pragma unroll
        for (int kk = 0; kk < 64; kk += 32){
            short8 af[4], bf[4];
            #pragma unroll
            for (int mt = 0; mt < 4; mt++)
                af[mt] = *(const short8*)&As[(wr * 64 + mt * 16 + mi) * LDT64 + kk + quad * 8];
            #pragma unroll
            for (int nt = 0; nt < 4; nt++)
                bf[nt] = *(const short8*)&Bs[(wc * 64 + nt * 16 + mi) * LDT64 + kk + quad * 8];
            #pragma unroll
            for (int mt = 0; mt < 4; mt++)
                #pragma unroll
                for (int nt = 0; nt < 4; nt++)
                    acc[mt][nt] = __builtin_amdgcn_mfma_f32_16x16x32_bf16(af[mt], bf[nt], acc[mt][nt], 0, 0, 0);
        }
    }

    // ---- coalesced epilogue: per-wave C-subtile through LDS ----
    float bv[4];
    if (MODE == 1){
        #pragma unroll
        for (int nt = 0; nt < 4; nt++) bv[nt] = bias[n0 + wc * 64 + nt * 16 + mi];
    }
    __syncthreads();                       // all ds_reads of last K-iter done; reuse As
    u16* cs = &As[w * 16 * LDT64];         // 16x72 u16 per wave
    int erow = lane >> 2, ecol = (lane & 3) * 16;
    #pragma unroll
    for (int mt = 0; mt < 4; mt++){
        #pragma unroll
        for (int nt = 0; nt < 4; nt++)
            #pragma unroll
            for (int r = 0; r < 4; r++){
                float v = acc[mt][nt][r];
                if (MODE == 1) v = gelu_exact(v + bv[nt]);
                cs[(quad * 4 + r) * LDT64 + nt * 16 + mi] = f2bf(v);
            }
        // wave-internal write->read (DS ops in-order within a wave; compiler waits lgkmcnt)
        uint4 c0 = *(const uint4*)&cs[erow * LDT64 + ecol];
        uint4 c1 = *(const uint4*)&cs[erow * LDT64 + ecol + 8];
        u16* cp = Cout + (size_t)(m0 + wr * 64 + mt * 16 + erow) * N + n0 + wc * 64 + ecol;
        *(uint4*)cp       = c0;
        *(uint4*)(cp + 8) = c1;
    }
}

// ---------------- 64x64-tile GEMM, BK=64, fp32 residual RMW, coalesced LDS epilogue ----------------
// xres[m][n] += acc + bias  (each block owns a distinct tile: plain RMW, no atomics)
__global__ __launch_bounds__(256) void k_gemm64_res(const u16* __restrict__ A,
                                                    const u16* __restrict__ Bt,
                                                    const float* __restrict__ bias,
                                                    float* __restrict__ xres,
                                                    int M, int N, int K){
    __shared__ u16 As[64 * LDT64];
    __shared__ u16 Bs[64 * LDT64];
    int m0 = blockIdx.y * 64, n0 = blockIdx.x * 64;
    int t = threadIdx.x;
    int w = t >> 6, lane = t & 63;
    int mi = lane & 15, quad = lane >> 4;
    int srow = t >> 2, scol = (t & 3) * 16;          // 64 rows x 64 k / 256 thr

    const u16* ag = A  + (size_t)(m0 + srow) * K + scol;
    const u16* bg = Bt + (size_t)(n0 + srow) * K + scol;

    f32x4 acc[4];
    #pragma unroll
    for (int tt = 0; tt < 4; tt++) acc[tt] = (f32x4){0.f, 0.f, 0.f, 0.f};

    for (int k0 = 0; k0 < K; k0 += 64){
        uint4 a0 = *(const uint4*)(ag + k0);
        uint4 a1 = *(const uint4*)(ag + k0 + 8);
        uint4 b0 = *(const uint4*)(bg + k0);
        uint4 b1 = *(const uint4*)(bg + k0 + 8);
        __syncthreads();
        *(uint4*)&As[srow * LDT64 + scol]     = a0;
        *(uint4*)&As[srow * LDT64 + scol + 8] = a1;
        *(uint4*)&Bs[srow * LDT64 + scol]     = b0;
        *(uint4*)&Bs[srow * LDT64 + scol + 8] = b1;
        __syncthreads();
        short8 af0 = *(const short8*)&As[(w * 16 + mi) * LDT64 + quad * 8];
        short8 af1 = *(const short8*)&As[(w * 16 + mi) * LDT64 + quad * 8 + 32];
        #pragma unroll
        for (int tt = 0; tt < 4; tt++){
            short8 bf0 = *(const short8*)&Bs[(tt * 16 + mi) * LDT64 + quad * 8];
            short8 bf1 = *(const short8*)&Bs[(tt * 16 + mi) * LDT64 + quad * 8 + 32];
            acc[tt] = __builtin_amdgcn_mfma_f32_16x16x32_bf16(af0, bf0, acc[tt], 0, 0, 0);
            acc[tt] = __builtin_amdgcn_mfma_f32_16x16x32_bf16(af1, bf1, acc[tt], 0, 0, 0);
        }
    }

    // ---- coalesced fp32 RMW epilogue through LDS ----
    float bv[4];
    #pragma unroll
    for (int tt = 0; tt < 4; tt++) bv[tt] = bias[n0 + tt * 16 + mi];
    __syncthreads();
    // per-wave 16x72 fp32 region: waves 0,1 in As (2304 floats), 2,3 in Bs
    float* cs = (w < 2) ? ((float*)As + w * 16 * LDT64)
                        : ((float*)Bs + (w - 2) * 16 * LDT64);
    #pragma unroll
    for (int tt = 0; tt < 4; tt++)
        #pragma unroll
        for (int r = 0; r < 4; r++)
            cs[(quad * 4 + r) * LDT64 + tt * 16 + mi] = acc[tt][r] + bv[tt];
    int erow = lane >> 2, ecol = (lane & 3) * 16;
    float* xp = xres + (size_t)(m0 + w * 16 + erow) * N + n0 + ecol;
    #pragma unroll
    for (int j = 0; j < 4; j++){
        float4 cv = *(const float4*)&cs[erow * LDT64 + ecol + j * 4];
        float4 xv = *(const float4*)(xp + j * 4);
        xv.x += cv.x; xv.y += cv.y; xv.z += cv.z; xv.w += cv.w;
        *(float4*)(xp + j * 4) = xv;
    }
}

// ---------------- MFMA flash attention v2: 8-wave blocks, phase-split wave roles ----------------
// Per block: 128 q-rows of one (b,h). 16 K/V tiles of 64 keys.
// QK phase: wave w -> (qh64=w>>2, nb=w&3): S[qh64*64..+63][nb*16..+15]; only 2 kb frags/wave.
// PV phase: wave w -> (qs=w&3, dh=w>>2): O[qs*32..+31][dims dh*32..+31]; 4 a + 4 vb frags/wave.
// l via constant-ones B-fragment MFMA, per-wave-unique 16-row block, exchanged through lrow[].
#define LDK 72
#define C1_LOG2E 0.18033688011112042f   // 0.125 * log2(e)
#define C2_LOG2E 11.541560327111707f    // 8 * log2(e)

__global__ __launch_bounds__(512, 4) void k_flash(const u16* __restrict__ qkv, u16* __restrict__ out){
    __shared__ u16 Ks[64 * LDK];        // [key][dim]
    __shared__ u16 Vt[64 * LDK];        // [dim][key]
    __shared__ u16 Ps[128 * LDK];       // [qrow][key], shared across waves
    __shared__ float lrow[128];

    // XCD-bijective swizzle: nwg=512, cpx=64 -> XCD k owns batch k (8 heads x 256KB K/V = 2MB in L2)
    int wg = (blockIdx.x & 7) * 64 + (blockIdx.x >> 3);
    int qt = wg & 7, h = (wg >> 3) & 7, b = wg >> 6;
    int t = threadIdx.x;
    int w = t >> 6, lane = t & 63;
    int mi = lane & 15, quad = lane >> 4;

    const u16* base = qkv + ((size_t)b * 1024) * 1536;
    int hoff = h * 64;

    int qh64 = w >> 2, nb = w & 3;      // QK role
    int qs = w & 3, dh = w >> 2;        // PV role

    // Q fragments: 64 rows x 64 dims for this wave's QK half
    short8 qf[4][2];
    #pragma unroll
    for (int qb = 0; qb < 4; qb++){
        int qrow = qt * 128 + qh64 * 64 + qb * 16 + mi;
        const u16* qp = base + (size_t)qrow * 1536 + hoff + quad * 8;
        qf[qb][0] = *(const short8*)(qp);
        qf[qb][1] = *(const short8*)(qp + 32);
    }

    f32x4 o[2][2];                      // [qb16][nd16] of the wave's 32x32 PV block
    f32x4 lacc;
    #pragma unroll
    for (int i = 0; i < 2; i++)
        #pragma unroll
        for (int j = 0; j < 2; j++) o[i][j] = (f32x4){0.f, 0.f, 0.f, 0.f};
    lacc = (f32x4){0.f, 0.f, 0.f, 0.f};

    short8 ones;
    #pragma unroll
    for (int i = 0; i < 8; i++) ones[i] = (short)0x3F80;   // bf16 1.0

    int kkey = t >> 3, kseg = t & 7;
    const u16* kgp = base + (size_t)kkey * 1536 + 512 + hoff + kseg * 8;
    int vkey = lane, vd0 = w * 8;
    const u16* vgp = base + (size_t)vkey * 1536 + 1024 + hoff + vd0;

    for (int kt = 0; kt < 16; kt++){
        size_t koff = (size_t)kt * 64 * 1536;
        uint4 kv = *(const uint4*)(kgp + koff);
        uint4 vv = *(const uint4*)(vgp + koff);
        __syncthreads();                               // prev tile's QK/PV reads done
        *(uint4*)&Ks[kkey * LDK + kseg * 8] = kv;
        u16 vtmp[8];
        *(uint4*)&vtmp[0] = vv;
        #pragma unroll
        for (int i = 0; i < 8; i++)
            Vt[(vd0 + i) * LDK + vkey] = vtmp[i];      // lane/2 spans 32 banks: conflict-free
        __syncthreads();

        // ---- QK: S = Q K^T over this wave's (64 rows x 16 keys), P -> Ps ----
        short8 kb0 = *(const short8*)&Ks[(nb * 16 + mi) * LDK + quad * 8];
        short8 kb1 = *(const short8*)&Ks[(nb * 16 + mi) * LDK + quad * 8 + 32];
        #pragma unroll
        for (int qb = 0; qb < 4; qb++){
            f32x4 z = (f32x4){0.f, 0.f, 0.f, 0.f};
            z = __builtin_amdgcn_mfma_f32_16x16x32_bf16(qf[qb][0], kb0, z, 0, 0, 0);
            z = __builtin_amdgcn_mfma_f32_16x16x32_bf16(qf[qb][1], kb1, z, 0, 0, 0);
            float e0 = exp2f(fmaf(z[0], C1_LOG2E, -C2_LOG2E));
            float e1 = exp2f(fmaf(z[1], C1_LOG2E, -C2_LOG2E));
            float e2 = exp2f(fmaf(z[2], C1_LOG2E, -C2_LOG2E));
            float e3 = exp2f(fmaf(z[3], C1_LOG2E, -C2_LOG2E));
            u32 p01 = cvt_pk_bf16(e0, e1);
            u32 p23 = cvt_pk_bf16(e2, e3);
            u16* pp = &Ps[(qh64 * 64 + qb * 16 + quad * 4) * LDK + nb * 16 + mi];
            pp[0]       = (u16)p01;
            pp[LDK]     = (u16)(p01 >> 16);
            pp[2 * LDK] = (u16)p23;
            pp[3 * LDK] = (u16)(p23 >> 16);
        }
        __syncthreads();                               // Ps complete for all waves

        // ---- PV: O += P V over this wave's (32 rows x 32 dims); l += P 1 ----
        short8 a[2][2], vb[2][2];
        #pragma unroll
        for (int qb = 0; qb < 2; qb++){
            a[qb][0] = *(const short8*)&Ps[(qs * 32 + qb * 16 + mi) * LDK + quad * 8];
            a[qb][1] = *(const short8*)&Ps[(qs * 32 + qb * 16 + mi) * LDK + quad * 8 + 32];
        }
        #pragma unroll
        for (int nd = 0; nd < 2; nd++){
            vb[nd][0] = *(const short8*)&Vt[(dh * 32 + nd * 16 + mi) * LDK + quad * 8];
            vb[nd][1] = *(const short8*)&Vt[(dh * 32 + nd * 16 + mi) * LDK + quad * 8 + 32];
        }
        #pragma unroll
        for (int qb = 0; qb < 2; qb++)
            #pragma unroll
            for (int nd = 0; nd < 2; nd++){
                o[qb][nd] = __builtin_amdgcn_mfma_f32_16x16x32_bf16(a[qb][0], vb[nd][0], o[qb][nd], 0, 0, 0);
                o[qb][nd] = __builtin_amdgcn_mfma_f32_16x16x32_bf16(a[qb][1], vb[nd][1], o[qb][nd], 0, 0, 0);
            }
        // l for rows qs*32 + dh*16 .. +15 ((qs,dh) covers all 8 row-blocks exactly once)
        lacc = __builtin_amdgcn_mfma_f32_16x16x32_bf16(a[dh][0], ones, lacc, 0, 0, 0);
        lacc = __builtin_amdgcn_mfma_f32_16x16x32_bf16(a[dh][1], ones, lacc, 0, 0, 0);
    }

    if (mi == 0){                                      // lanes 0,16,32,48: quad gives 4 rows each
        #pragma unroll
        for (int r = 0; r < 4; r++)
            lrow[qs * 32 + dh * 16 + quad * 4 + r] = lacc[r];
    }
    __syncthreads();

    u16* op = out + ((size_t)b * 1024 + qt * 128 + qs * 32) * 512 + hoff + dh * 32;
    #pragma unroll
    for (int qb = 0; qb < 2; qb++){
        float invl[4];
        #pragma unroll
        for (int r = 0; r < 4; r++)
            invl[r] = 1.f / lrow[qs * 32 + qb * 16 + quad * 4 + r];
        #pragma unroll
        for (int nd = 0; nd < 2; nd++){
            u32 c01 = cvt_pk_bf16(o[qb][nd][0] * invl[0], o[qb][nd][1] * invl[1]);
            u32 c23 = cvt_pk_bf16(o[qb][nd][2] * invl[2], o[qb][nd][3] * invl[3]);
            u16* cp = op + (size_t)(qb * 16 + quad * 4) * 512 + nd * 16 + mi;
            cp[0]       = (u16)c01;
            cp[512]     = (u16)(c01 >> 16);
            cp[2 * 512] = (u16)c23;
            cp[3 * 512] = (u16)(c23 >> 16);
        }
    }
}

// ---------------- host launch ----------------
extern "C" void kernel_launch(void* const* d_in, const int* in_sizes, int n_in,
                              void* d_out, int out_size, void* d_ws, size_t ws_size,
                              hipStream_t stream){
    const float* x_in  = (const float*)d_in[0];
    const float* ln1_s = (const float*)d_in[1];
    const float* ln1_b = (const float*)d_in[2];
    const float* w_qkv = (const float*)d_in[3];
    const float* w_out = (const float*)d_in[4];
    const float* b_out = (const float*)d_in[5];
    const float* ln2_s = (const float*)d_in[6];
    const float* ln2_b = (const float*)d_in[7];
    const float* w1    = (const float*)d_in[8];
    const float* b1    = (const float*)d_in[9];
    const float* w2    = (const float*)d_in[10];
    const float* b2    = (const float*)d_in[11];
    float* out = (float*)d_out;

    char* ws = (char*)d_ws;
    float* x_f32 = (float*)ws;   ws += (size_t)M_TOK * DIMM * 4;      // 16 MB fp32 residual
    u16* bufA    = (u16*)ws;     ws += (size_t)M_TOK * DIMM * 2;      // 8 MB  (ln_out / attn_out)
    u16* bufB    = (u16*)ws;     ws += (size_t)M_TOK * MLPD * 2;      // 32 MB (qkv / mlp_h)
    u16* wbase   = (u16*)ws;
    size_t per_layer_w = (size_t)(1536 + 512 + 2048 + 2048) * 512;    // 6 MB

    size_t used_big = (size_t)(ws - (char*)d_ws) + per_layer_w * 2 * DEPTH;
    bool big = (ws_size >= used_big);

    u16* ln_out   = bufA;
    u16* attn_out = bufA;
    u16* qkv      = bufB;
    u16* mlp_h    = bufB;

    size_t x_bytes = (size_t)M_TOK * DIMM * sizeof(float);
    hipMemcpyAsync(x_f32, x_in, x_bytes, hipMemcpyDeviceToDevice, stream);

    const size_t off_qkv = 0;
    const size_t off_out = (size_t)1536 * 512;
    const size_t off_w1  = off_out + (size_t)512 * 512;
    const size_t off_w2  = off_w1 + (size_t)2048 * 512;

    if (big){
        k_transpose_cvt<<<dim3(48, 16, 6), dim3(32, 8), 0, stream>>>(w_qkv, wbase + off_qkv * DEPTH, 512, 1536);
        k_transpose_cvt<<<dim3(16, 16, 6), dim3(32, 8), 0, stream>>>(w_out, wbase + off_out * DEPTH, 512, 512);
        k_transpose_cvt<<<dim3(64, 16, 6), dim3(32, 8), 0, stream>>>(w1,    wbase + off_w1  * DEPTH, 512, 2048);
        k_transpose_cvt<<<dim3(16, 64, 6), dim3(32, 8), 0, stream>>>(w2,    wbase + off_w2  * DEPTH, 2048, 512);
    }

    for (int i = 0; i < DEPTH; i++){
        u16 *wqkvT, *woutT, *w1T, *w2T;
        if (big){
            wqkvT = wbase + off_qkv * DEPTH + (size_t)i * 1536 * 512;
            woutT = wbase + off_out * DEPTH + (size_t)i * 512 * 512;
            w1T   = wbase + off_w1  * DEPTH + (size_t)i * 2048 * 512;
            w2T   = wbase + off_w2  * DEPTH + (size_t)i * 512 * 2048;
        } else {
            wqkvT = wbase + off_qkv; woutT = wbase + off_out;
            w1T   = wbase + off_w1;  w2T   = wbase + off_w2;
            k_transpose_cvt<<<dim3(48, 16), dim3(32, 8), 0, stream>>>(w_qkv + (size_t)i * 512 * 1536, wqkvT, 512, 1536);
            k_transpose_cvt<<<dim3(16, 16), dim3(32, 8), 0, stream>>>(w_out + (size_t)i * 512 * 512,  woutT, 512, 512);
            k_transpose_cvt<<<dim3(64, 16), dim3(32, 8), 0, stream>>>(w1    + (size_t)i * 512 * 2048, w1T,   512, 2048);
            k_transpose_cvt<<<dim3(16, 64), dim3(32, 8), 0, stream>>>(w2    + (size_t)i * 2048 * 512, w2T,   2048, 512);
        }

        k_layernorm<<<dim3(M_TOK / 4), dim3(256), 0, stream>>>(x_f32, ln1_s + i * 512, ln1_b + i * 512, ln_out);
        k_gemm128b<0><<<dim3(12, 64), dim3(256), 0, stream>>>(ln_out, wqkvT, nullptr, qkv,
                                                              M_TOK, 1536, 512);
        k_flash<<<dim3(512), dim3(512), 0, stream>>>(qkv, attn_out);
        k_gemm64_res<<<dim3(8, 128), dim3(256), 0, stream>>>(attn_out, woutT, b_out + i * 512, x_f32,
                                                             M_TOK, 512, 512);
        k_layernorm<<<dim3(M_TOK / 4), dim3(256), 0, stream>>>(x_f32, ln2_s + i * 512, ln2_b + i * 512, ln_out);
        k_gemm128b<1><<<dim3(16, 64), dim3(256), 0, stream>>>(ln_out, w1T, b1 + i * 2048, mlp_h,
                                                              M_TOK, 2048, 512);
        k_gemm64_res<<<dim3(8, 128), dim3(256), 0, stream>>>(mlp_h, w2T, b2 + i * 512, x_f32,
                                                             M_TOK, 512, 2048);
    }
    hipMemcpyAsync(out, x_f32, x_bytes, hipMemcpyDeviceToDevice, stream);
}

// Round 2
// 1332.365 us; speedup vs baseline: 1.3683x; 1.3683x over previous
//
#include <hip/hip_runtime.h>
#include <cstdint>
#include <cstddef>

#define M_TOK 8192
#define DIMM  512
#define HEADS 8
#define DH    64
#define MLPD  2048
#define DEPTH 6

typedef unsigned short u16;
typedef unsigned int   u32;
typedef __attribute__((ext_vector_type(8))) short short8;   // 8 bf16 (4 VGPRs)
typedef __attribute__((ext_vector_type(4))) float f32x4;    // 4 fp32 acc

__device__ __forceinline__ float bf2f(u16 u){ return __uint_as_float(((u32)u) << 16); }
__device__ __forceinline__ u16 f2bf(float f){
    u32 x = __float_as_uint(f);
    u32 r = x + 0x7fffu + ((x >> 16) & 1u);   // RNE
    return (u16)(r >> 16);
}
// packed f32x2 -> bf16x2 (RNE), 1 instr for 2 converts
__device__ __forceinline__ u32 cvt_pk_bf16(float a, float b){
    u32 r;
    asm("v_cvt_pk_bf16_f32 %0, %1, %2" : "=v"(r) : "v"(a), "v"(b));
    return r;
}
// async global->LDS, 16B per lane; lds dest must be wave-uniform base (lane*16 implicit)
__device__ __forceinline__ void async16(const u16* g, u16* l){
    __builtin_amdgcn_global_load_lds(
        (const __attribute__((address_space(1))) void*)(uintptr_t)(const void*)g,
        (__attribute__((address_space(3))) void*)(u32)(uintptr_t)(void*)l,
        16, 0, 0);
}

// ---------------- weight transpose + cvt: fp32 in[R][C] -> bf16 out[C][R], z layers ----------------
__global__ void k_transpose_cvt(const float* __restrict__ in, u16* __restrict__ out, int R, int C){
    __shared__ u16 tile[32][33];
    size_t zoff = (size_t)blockIdx.z * R * C;
    in += zoff; out += zoff;
    int c0 = blockIdx.x * 32, r0 = blockIdx.y * 32;
    int tx = threadIdx.x, ty = threadIdx.y;           // (32, 8)
    #pragma unroll
    for (int i = 0; i < 32; i += 8)
        tile[ty + i][tx] = f2bf(in[(size_t)(r0 + ty + i) * C + c0 + tx]);
    __syncthreads();
    #pragma unroll
    for (int i = 0; i < 32; i += 8)
        out[(size_t)(c0 + ty + i) * R + r0 + tx] = tile[tx][ty + i];
}

// ---------------- LayerNorm: fp32 x row -> bf16 out; 4 rows/block, 1 wave/row ----------------
__global__ __launch_bounds__(256) void k_layernorm(const float* __restrict__ x,
                                                   const float* __restrict__ s,
                                                   const float* __restrict__ b,
                                                   u16* __restrict__ out){
    int row = blockIdx.x * 4 + (threadIdx.x >> 6);
    int lane = threadIdx.x & 63;
    const float* xp = x + (size_t)row * DIMM + lane * 8;
    float v[8];
    #pragma unroll
    for (int c = 0; c < 8; c++) v[c] = xp[c];
    float sum = 0.f, sq = 0.f;
    #pragma unroll
    for (int c = 0; c < 8; c++){ sum += v[c]; sq += v[c] * v[c]; }
    #pragma unroll
    for (int m = 32; m >= 1; m >>= 1){
        sum += __shfl_xor(sum, m);
        sq  += __shfl_xor(sq,  m);
    }
    float mu  = sum * (1.f / DIMM);
    float var = sq * (1.f / DIMM) - mu * mu;
    float rs  = rsqrtf(var + 1e-5f);
    u16* op = out + (size_t)row * DIMM + lane * 8;
    #pragma unroll
    for (int c = 0; c < 8; c++){
        int col = lane * 8 + c;
        op[c] = f2bf((v[c] - mu) * rs * s[col] + b[col]);
    }
}

__device__ __forceinline__ float gelu_exact(float v){
    return 0.5f * v * (1.f + erff(v * 0.70710678118654752f));
}

#define LDT64 72   // padded stride for epilogue LDS scratch only

// ---------------- 128x128-tile GEMM, BK=64, global_load_lds staging (m97 pattern) ----------------
// LDS tiles are LINEAR [128][64] u16 (gload_lds needs lane-contiguous dest).
// MODE 0: Cout=bf16(acc); MODE 1: Cout=bf16(gelu(acc+bias)).
template<int MODE>
__global__ __launch_bounds__(256) void k_gemm128b(const u16* __restrict__ A,
                                                  const u16* __restrict__ Bt,
                                                  const float* __restrict__ bias,
                                                  u16* __restrict__ Cout,
                                                  int M, int N, int K){
    __shared__ u16 As[128 * LDT64];   // staging uses first 128*64; epilogue scratch uses LDT64 stride
    __shared__ u16 Bs[128 * LDT64];
    int m0 = blockIdx.y * 128, n0 = blockIdx.x * 128;
    int t = threadIdx.x;
    int w = t >> 6, lane = t & 63;
    int mi = lane & 15, quad = lane >> 4;
    int wr = w >> 1, wc = w & 1;

    // gload addressing: wave w stages rows w*32..w*32+31 of each matrix.
    // one async16 covers 8 rows: lane l -> row +(l>>3), cols (l&7)*8..+7
    int grow = lane >> 3, gcol = (lane & 7) * 8;
    const u16* agl = A  + (size_t)(m0 + w * 32 + grow) * K + gcol;
    const u16* bgl = Bt + (size_t)(n0 + w * 32 + grow) * K + gcol;
    u16* asl = &As[(w * 32) * 64];
    u16* bsl = &Bs[(w * 32) * 64];

    f32x4 acc[4][4];
    #pragma unroll
    for (int mt = 0; mt < 4; mt++)
        #pragma unroll
        for (int nt = 0; nt < 4; nt++) acc[mt][nt] = (f32x4){0.f, 0.f, 0.f, 0.f};

    for (int k0 = 0; k0 < K; k0 += 64){
        __syncthreads();                       // prev iter's ds_reads done
        #pragma unroll
        for (int i = 0; i < 4; i++){
            async16(agl + (size_t)(i * 8) * K + k0, asl + i * 8 * 64);
            async16(bgl + (size_t)(i * 8) * K + k0, bsl + i * 8 * 64);
        }
        __syncthreads();                       // compiler drains vmcnt(0) before barrier
        #pragma unroll
        for (int kk = 0; kk < 64; kk += 32){
            short8 af[4], bf[4];
            #pragma unroll
            for (int mt = 0; mt < 4; mt++)
                af[mt] = *(const short8*)&As[(wr * 64 + mt * 16 + mi) * 64 + kk + quad * 8];
            #pragma unroll
            for (int nt = 0; nt < 4; nt++)
                bf[nt] = *(const short8*)&Bs[(wc * 64 + nt * 16 + mi) * 64 + kk + quad * 8];
            #pragma unroll
            for (int mt = 0; mt < 4; mt++)
                #pragma unroll
                for (int nt = 0; nt < 4; nt++)
                    acc[mt][nt] = __builtin_amdgcn_mfma_f32_16x16x32_bf16(af[mt], bf[nt], acc[mt][nt], 0, 0, 0);
        }
    }

    // ---- coalesced epilogue: per-wave C-subtile through LDS (LDT64-stride scratch) ----
    float bv[4];
    if (MODE == 1){
        #pragma unroll
        for (int nt = 0; nt < 4; nt++) bv[nt] = bias[n0 + wc * 64 + nt * 16 + mi];
    }
    __syncthreads();                       // all ds_reads of last K-iter done; reuse As
    u16* cs = &As[w * 16 * LDT64];         // 16x72 u16 per wave
    int erow = lane >> 2, ecol = (lane & 3) * 16;
    #pragma unroll
    for (int mt = 0; mt < 4; mt++){
        #pragma unroll
        for (int nt = 0; nt < 4; nt++)
            #pragma unroll
            for (int r = 0; r < 4; r++){
                float v = acc[mt][nt][r];
                if (MODE == 1) v = gelu_exact(v + bv[nt]);
                cs[(quad * 4 + r) * LDT64 + nt * 16 + mi] = f2bf(v);
            }
        // wave-internal write->read (DS ops in-order within a wave; compiler waits lgkmcnt)
        uint4 c0 = *(const uint4*)&cs[erow * LDT64 + ecol];
        uint4 c1 = *(const uint4*)&cs[erow * LDT64 + ecol + 8];
        u16* cp = Cout + (size_t)(m0 + wr * 64 + mt * 16 + erow) * N + n0 + wc * 64 + ecol;
        *(uint4*)cp       = c0;
        *(uint4*)(cp + 8) = c1;
    }
}

// ---------------- 64x64-tile GEMM, BK=64, global_load_lds staging, fp32 residual RMW ----------------
// xres[m][n] += acc + bias  (each block owns a distinct tile: plain RMW, no atomics)
__global__ __launch_bounds__(256) void k_gemm64_res(const u16* __restrict__ A,
                                                    const u16* __restrict__ Bt,
                                                    const float* __restrict__ bias,
                                                    float* __restrict__ xres,
                                                    int M, int N, int K){
    __shared__ u16 As[64 * LDT64];    // staging first 64*64; epilogue fp32 scratch LDT64 stride
    __shared__ u16 Bs[64 * LDT64];
    int m0 = blockIdx.y * 64, n0 = blockIdx.x * 64;
    int t = threadIdx.x;
    int w = t >> 6, lane = t & 63;
    int mi = lane & 15, quad = lane >> 4;

    // wave w stages rows w*16..w*16+15 of each matrix (2 async16 each)
    int grow = lane >> 3, gcol = (lane & 7) * 8;
    const u16* agl = A  + (size_t)(m0 + w * 16 + grow) * K + gcol;
    const u16* bgl = Bt + (size_t)(n0 + w * 16 + grow) * K + gcol;
    u16* asl = &As[(w * 16) * 64];
    u16* bsl = &Bs[(w * 16) * 64];

    f32x4 acc[4];
    #pragma unroll
    for (int tt = 0; tt < 4; tt++) acc[tt] = (f32x4){0.f, 0.f, 0.f, 0.f};

    for (int k0 = 0; k0 < K; k0 += 64){
        __syncthreads();
        #pragma unroll
        for (int i = 0; i < 2; i++){
            async16(agl + (size_t)(i * 8) * K + k0, asl + i * 8 * 64);
            async16(bgl + (size_t)(i * 8) * K + k0, bsl + i * 8 * 64);
        }
        __syncthreads();
        short8 af0 = *(const short8*)&As[(w * 16 + mi) * 64 + quad * 8];
        short8 af1 = *(const short8*)&As[(w * 16 + mi) * 64 + quad * 8 + 32];
        #pragma unroll
        for (int tt = 0; tt < 4; tt++){
            short8 bf0 = *(const short8*)&Bs[(tt * 16 + mi) * 64 + quad * 8];
            short8 bf1 = *(const short8*)&Bs[(tt * 16 + mi) * 64 + quad * 8 + 32];
            acc[tt] = __builtin_amdgcn_mfma_f32_16x16x32_bf16(af0, bf0, acc[tt], 0, 0, 0);
            acc[tt] = __builtin_amdgcn_mfma_f32_16x16x32_bf16(af1, bf1, acc[tt], 0, 0, 0);
        }
    }

    // ---- coalesced fp32 RMW epilogue through LDS ----
    float bv[4];
    #pragma unroll
    for (int tt = 0; tt < 4; tt++) bv[tt] = bias[n0 + tt * 16 + mi];
    __syncthreads();
    // per-wave 16x72 fp32 region: waves 0,1 in As (2304 floats), 2,3 in Bs
    float* cs = (w < 2) ? ((float*)As + w * 16 * LDT64)
                        : ((float*)Bs + (w - 2) * 16 * LDT64);
    #pragma unroll
    for (int tt = 0; tt < 4; tt++)
        #pragma unroll
        for (int r = 0; r < 4; r++)
            cs[(quad * 4 + r) * LDT64 + tt * 16 + mi] = acc[tt][r] + bv[tt];
    int erow = lane >> 2, ecol = (lane & 3) * 16;
    float* xp = xres + (size_t)(m0 + w * 16 + erow) * N + n0 + ecol;
    #pragma unroll
    for (int j = 0; j < 4; j++){
        float4 cv = *(const float4*)&cs[erow * LDT64 + ecol + j * 4];
        float4 xv = *(const float4*)(xp + j * 4);
        xv.x += cv.x; xv.y += cv.y; xv.z += cv.z; xv.w += cv.w;
        *(float4*)(xp + j * 4) = xv;
    }
}

// ---------------- MFMA flash attention (round-0 structure + XCD swizzle + cvt_pk) ----------------
#define LDK 72
#define C1_LOG2E 0.18033688011112042f   // 0.125 * log2(e)
#define C2_LOG2E 11.541560327111707f    // 8 * log2(e)

__global__ __launch_bounds__(256) void k_flash(const u16* __restrict__ qkv, u16* __restrict__ out){
    __shared__ u16 Ks[64 * LDK];        // [key][dim]
    __shared__ u16 Vt[80 * LDK];        // [dim][key]; rows 64..79 = 1.0 (l-accumulator)
    __shared__ u16 Ps[4][32 * LDK];     // per-wave P [q32][key]
    // XCD-bijective swizzle: nwg=512 -> XCD k owns batch k (8 heads x 256KB K/V = 2MB in its L2)
    int wg = (blockIdx.x & 7) * 64 + (blockIdx.x >> 3);
    int qt = wg & 7, h = (wg >> 3) & 7, b = wg >> 6;
    int t = threadIdx.x;
    int w = t >> 6, lane = t & 63;
    int mi = lane & 15, quad = lane >> 4;

    for (int i = t; i < 16 * 64; i += 256){
        int d = i >> 6, kk = i & 63;
        Vt[(64 + d) * LDK + kk] = 0x3F80;   // bf16 1.0
    }

    const u16* base = qkv + ((size_t)b * 1024) * 1536;
    int hoff = h * 64;

    short8 qf[2][2];
    #pragma unroll
    for (int qh = 0; qh < 2; qh++){
        int qrow = qt * 128 + w * 32 + qh * 16 + mi;
        const u16* qp = base + (size_t)qrow * 1536 + hoff + quad * 8;
        qf[qh][0] = *(const short8*)(qp);
        qf[qh][1] = *(const short8*)(qp + 32);
    }

    f32x4 o[2][4];
    f32x4 lacc[2];
    #pragma unroll
    for (int qh = 0; qh < 2; qh++){
        #pragma unroll
        for (int nb = 0; nb < 4; nb++) o[qh][nb] = (f32x4){0.f, 0.f, 0.f, 0.f};
        lacc[qh] = (f32x4){0.f, 0.f, 0.f, 0.f};
    }

    int kkey = t >> 2, kseg = t & 3;
    const u16* kgp = base + (size_t)kkey * 1536 + 512 + hoff + kseg * 16;
    int vkey = lane, vdg = w;
    const u16* vgp = base + (size_t)vkey * 1536 + 1024 + hoff + vdg * 16;

    for (int kt = 0; kt < 16; kt++){
        size_t koff = (size_t)kt * 64 * 1536;
        uint4 kv0 = *(const uint4*)(kgp + koff);
        uint4 kv1 = *(const uint4*)(kgp + koff + 8);
        uint4 vv0 = *(const uint4*)(vgp + koff);
        uint4 vv1 = *(const uint4*)(vgp + koff + 8);
        __syncthreads();
        *(uint4*)&Ks[kkey * LDK + kseg * 16]     = kv0;
        *(uint4*)&Ks[kkey * LDK + kseg * 16 + 8] = kv1;
        u16 vtmp[16];
        *(uint4*)&vtmp[0] = vv0;
        *(uint4*)&vtmp[8] = vv1;
        #pragma unroll
        for (int i = 0; i < 16; i++)
            Vt[(vdg * 16 + i) * LDK + vkey] = vtmp[i];   // 2 lanes/bank = free
        __syncthreads();

        // ---- K fragments once, shared by both q-halves ----
        short8 kb[4][2];
        #pragma unroll
        for (int nb = 0; nb < 4; nb++){
            kb[nb][0] = *(const short8*)&Ks[(nb * 16 + mi) * LDK + quad * 8];
            kb[nb][1] = *(const short8*)&Ks[(nb * 16 + mi) * LDK + quad * 8 + 32];
        }
        // ---- S = Q K^T, P = exp2(S*c1 - c2) -> LDS (packed bf16 converts) ----
        #pragma unroll
        for (int qh = 0; qh < 2; qh++){
            #pragma unroll
            for (int nb = 0; nb < 4; nb++){
                f32x4 z = (f32x4){0.f, 0.f, 0.f, 0.f};
                z = __builtin_amdgcn_mfma_f32_16x16x32_bf16(qf[qh][0], kb[nb][0], z, 0, 0, 0);
                z = __builtin_amdgcn_mfma_f32_16x16x32_bf16(qf[qh][1], kb[nb][1], z, 0, 0, 0);
                float e0 = exp2f(fmaf(z[0], C1_LOG2E, -C2_LOG2E));
                float e1 = exp2f(fmaf(z[1], C1_LOG2E, -C2_LOG2E));
                float e2 = exp2f(fmaf(z[2], C1_LOG2E, -C2_LOG2E));
                float e3 = exp2f(fmaf(z[3], C1_LOG2E, -C2_LOG2E));
                u32 p01 = cvt_pk_bf16(e0, e1);
                u32 p23 = cvt_pk_bf16(e2, e3);
                u16* pp = &Ps[w][(qh * 16 + quad * 4) * LDK + nb * 16 + mi];
                pp[0]       = (u16)p01;
                pp[LDK]     = (u16)(p01 >> 16);
                pp[2 * LDK] = (u16)p23;
                pp[3 * LDK] = (u16)(p23 >> 16);
            }
        }
        // ---- V fragments once ----
        short8 vb[4][2], lb[2];
        #pragma unroll
        for (int nb = 0; nb < 4; nb++){
            vb[nb][0] = *(const short8*)&Vt[(nb * 16 + mi) * LDK + quad * 8];
            vb[nb][1] = *(const short8*)&Vt[(nb * 16 + mi) * LDK + quad * 8 + 32];
        }
        lb[0] = *(const short8*)&Vt[(64 + mi) * LDK + quad * 8];
        lb[1] = *(const short8*)&Vt[(64 + mi) * LDK + quad * 8 + 32];
        // ---- O += P V ; l += P 1 ----
        #pragma unroll
        for (int qh = 0; qh < 2; qh++){
            const short8 a0 = *(const short8*)&Ps[w][(qh * 16 + mi) * LDK + quad * 8];
            const short8 a1 = *(const short8*)&Ps[w][(qh * 16 + mi) * LDK + quad * 8 + 32];
            #pragma unroll
            for (int nb = 0; nb < 4; nb++){
                o[qh][nb] = __builtin_amdgcn_mfma_f32_16x16x32_bf16(a0, vb[nb][0], o[qh][nb], 0, 0, 0);
                o[qh][nb] = __builtin_amdgcn_mfma_f32_16x16x32_bf16(a1, vb[nb][1], o[qh][nb], 0, 0, 0);
            }
            lacc[qh] = __builtin_amdgcn_mfma_f32_16x16x32_bf16(a0, lb[0], lacc[qh], 0, 0, 0);
            lacc[qh] = __builtin_amdgcn_mfma_f32_16x16x32_bf16(a1, lb[1], lacc[qh], 0, 0, 0);
        }
    }
    #pragma unroll
    for (int qh = 0; qh < 2; qh++){
        float invl[4];
        #pragma unroll
        for (int r = 0; r < 4; r++) invl[r] = 1.f / lacc[qh][r];
        u16* op = out + ((size_t)b * 1024 + qt * 128 + w * 32 + qh * 16) * 512 + hoff;
        #pragma unroll
        for (int nb = 0; nb < 4; nb++){
            u32 c01 = cvt_pk_bf16(o[qh][nb][0] * invl[0], o[qh][nb][1] * invl[1]);
            u32 c23 = cvt_pk_bf16(o[qh][nb][2] * invl[2], o[qh][nb][3] * invl[3]);
            u16* cp = op + (size_t)(quad * 4) * 512 + nb * 16 + mi;
            cp[0]       = (u16)c01;
            cp[512]     = (u16)(c01 >> 16);
            cp[2 * 512] = (u16)c23;
            cp[3 * 512] = (u16)(c23 >> 16);
        }
    }
}

// ---------------- host launch ----------------
extern "C" void kernel_launch(void* const* d_in, const int* in_sizes, int n_in,
                              void* d_out, int out_size, void* d_ws, size_t ws_size,
                              hipStream_t stream){
    const float* x_in  = (const float*)d_in[0];
    const float* ln1_s = (const float*)d_in[1];
    const float* ln1_b = (const float*)d_in[2];
    const float* w_qkv = (const float*)d_in[3];
    const float* w_out = (const float*)d_in[4];
    const float* b_out = (const float*)d_in[5];
    const float* ln2_s = (const float*)d_in[6];
    const float* ln2_b = (const float*)d_in[7];
    const float* w1    = (const float*)d_in[8];
    const float* b1    = (const float*)d_in[9];
    const float* w2    = (const float*)d_in[10];
    const float* b2    = (const float*)d_in[11];
    float* out = (float*)d_out;

    char* ws = (char*)d_ws;
    float* x_f32 = (float*)ws;   ws += (size_t)M_TOK * DIMM * 4;      // 16 MB fp32 residual
    u16* bufA    = (u16*)ws;     ws += (size_t)M_TOK * DIMM * 2;      // 8 MB  (ln_out / attn_out)
    u16* bufB    = (u16*)ws;     ws += (size_t)M_TOK * MLPD * 2;      // 32 MB (qkv / mlp_h)
    u16* wbase   = (u16*)ws;
    size_t per_layer_w = (size_t)(1536 + 512 + 2048 + 2048) * 512;    // 6 MB

    size_t used_big = (size_t)(ws - (char*)d_ws) + per_layer_w * 2 * DEPTH;
    bool big = (ws_size >= used_big);

    u16* ln_out   = bufA;
    u16* attn_out = bufA;
    u16* qkv      = bufB;
    u16* mlp_h    = bufB;

    size_t x_bytes = (size_t)M_TOK * DIMM * sizeof(float);
    hipMemcpyAsync(x_f32, x_in, x_bytes, hipMemcpyDeviceToDevice, stream);

    const size_t off_qkv = 0;
    const size_t off_out = (size_t)1536 * 512;
    const size_t off_w1  = off_out + (size_t)512 * 512;
    const size_t off_w2  = off_w1 + (size_t)2048 * 512;

    if (big){
        k_transpose_cvt<<<dim3(48, 16, 6), dim3(32, 8), 0, stream>>>(w_qkv, wbase + off_qkv * DEPTH, 512, 1536);
        k_transpose_cvt<<<dim3(16, 16, 6), dim3(32, 8), 0, stream>>>(w_out, wbase + off_out * DEPTH, 512, 512);
        k_transpose_cvt<<<dim3(64, 16, 6), dim3(32, 8), 0, stream>>>(w1,    wbase + off_w1  * DEPTH, 512, 2048);
        k_transpose_cvt<<<dim3(16, 64, 6), dim3(32, 8), 0, stream>>>(w2,    wbase + off_w2  * DEPTH, 2048, 512);
    }

    for (int i = 0; i < DEPTH; i++){
        u16 *wqkvT, *woutT, *w1T, *w2T;
        if (big){
            wqkvT = wbase + off_qkv * DEPTH + (size_t)i * 1536 * 512;
            woutT = wbase + off_out * DEPTH + (size_t)i * 512 * 512;
            w1T   = wbase + off_w1  * DEPTH + (size_t)i * 2048 * 512;
            w2T   = wbase + off_w2  * DEPTH + (size_t)i * 512 * 2048;
        } else {
            wqkvT = wbase + off_qkv; woutT = wbase + off_out;
            w1T   = wbase + off_w1;  w2T   = wbase + off_w2;
            k_transpose_cvt<<<dim3(48, 16), dim3(32, 8), 0, stream>>>(w_qkv + (size_t)i * 512 * 1536, wqkvT, 512, 1536);
            k_transpose_cvt<<<dim3(16, 16), dim3(32, 8), 0, stream>>>(w_out + (size_t)i * 512 * 512,  woutT, 512, 512);
            k_transpose_cvt<<<dim3(64, 16), dim3(32, 8), 0, stream>>>(w1    + (size_t)i * 512 * 2048, w1T,   512, 2048);
            k_transpose_cvt<<<dim3(16, 64), dim3(32, 8), 0, stream>>>(w2    + (size_t)i * 2048 * 512, w2T,   2048, 512);
        }

        k_layernorm<<<dim3(M_TOK / 4), dim3(256), 0, stream>>>(x_f32, ln1_s + i * 512, ln1_b + i * 512, ln_out);
        k_gemm128b<0><<<dim3(12, 64), dim3(256), 0, stream>>>(ln_out, wqkvT, nullptr, qkv,
                                                              M_TOK, 1536, 512);
        k_flash<<<dim3(512), dim3(256), 0, stream>>>(qkv, attn_out);
        k_gemm64_res<<<dim3(8, 128), dim3(256), 0, stream>>>(attn_out, woutT, b_out + i * 512, x_f32,
                                                             M_TOK, 512, 512);
        k_layernorm<<<dim3(M_TOK / 4), dim3(256), 0, stream>>>(x_f32, ln2_s + i * 512, ln2_b + i * 512, ln_out);
        k_gemm128b<1><<<dim3(16, 64), dim3(256), 0, stream>>>(ln_out, w1T, b1 + i * 2048, mlp_h,
                                                              M_TOK, 2048, 512);
        k_gemm64_res<<<dim3(8, 128), dim3(256), 0, stream>>>(mlp_h, w2T, b2 + i * 512, x_f32,
                                                             M_TOK, 512, 2048);
    }
    hipMemcpyAsync(out, x_f32, x_bytes, hipMemcpyDeviceToDevice, stream);
}

// Round 3
// 1263.387 us; speedup vs baseline: 1.4430x; 1.0546x over previous
//
#include <hip/hip_runtime.h>
#include <cstdint>
#include <cstddef>

#define M_TOK 8192
#define DIMM  512
#define HEADS 8
#define DH    64
#define MLPD  2048
#define DEPTH 6

typedef unsigned short u16;
typedef unsigned int   u32;
typedef __attribute__((ext_vector_type(8))) short short8;   // 8 bf16 (4 VGPRs)
typedef __attribute__((ext_vector_type(4))) float f32x4;    // 4 fp32 acc

__device__ __forceinline__ float bf2f(u16 u){ return __uint_as_float(((u32)u) << 16); }
__device__ __forceinline__ u16 f2bf(float f){
    u32 x = __float_as_uint(f);
    u32 r = x + 0x7fffu + ((x >> 16) & 1u);   // RNE
    return (u16)(r >> 16);
}
// packed f32x2 -> bf16x2 (RNE), 1 instr for 2 converts
__device__ __forceinline__ u32 cvt_pk_bf16(float a, float b){
    u32 r;
    asm("v_cvt_pk_bf16_f32 %0, %1, %2" : "=v"(r) : "v"(a), "v"(b));
    return r;
}
// async global->LDS, 16B per lane; lds dest must be wave-uniform base (lane*16 implicit)
__device__ __forceinline__ void async16(const u16* g, u16* l){
    __builtin_amdgcn_global_load_lds(
        (const __attribute__((address_space(1))) void*)(uintptr_t)(const void*)g,
        (__attribute__((address_space(3))) void*)(u32)(uintptr_t)(void*)l,
        16, 0, 0);
}

// ---------------- weight transpose + cvt: fp32 in[R][C] -> bf16 out[C][R], z layers ----------------
__global__ void k_transpose_cvt(const float* __restrict__ in, u16* __restrict__ out, int R, int C){
    __shared__ u16 tile[32][33];
    size_t zoff = (size_t)blockIdx.z * R * C;
    in += zoff; out += zoff;
    int c0 = blockIdx.x * 32, r0 = blockIdx.y * 32;
    int tx = threadIdx.x, ty = threadIdx.y;           // (32, 8)
    #pragma unroll
    for (int i = 0; i < 32; i += 8)
        tile[ty + i][tx] = f2bf(in[(size_t)(r0 + ty + i) * C + c0 + tx]);
    __syncthreads();
    #pragma unroll
    for (int i = 0; i < 32; i += 8)
        out[(size_t)(c0 + ty + i) * R + r0 + tx] = tile[tx][ty + i];
}

// ---------------- LayerNorm: fp32 x row -> bf16 out; 4 rows/block, 1 wave/row ----------------
__global__ __launch_bounds__(256) void k_layernorm(const float* __restrict__ x,
                                                   const float* __restrict__ s,
                                                   const float* __restrict__ b,
                                                   u16* __restrict__ out){
    int row = blockIdx.x * 4 + (threadIdx.x >> 6);
    int lane = threadIdx.x & 63;
    const float* xp = x + (size_t)row * DIMM + lane * 8;
    float v[8];
    #pragma unroll
    for (int c = 0; c < 8; c++) v[c] = xp[c];
    float sum = 0.f, sq = 0.f;
    #pragma unroll
    for (int c = 0; c < 8; c++){ sum += v[c]; sq += v[c] * v[c]; }
    #pragma unroll
    for (int m = 32; m >= 1; m >>= 1){
        sum += __shfl_xor(sum, m);
        sq  += __shfl_xor(sq,  m);
    }
    float mu  = sum * (1.f / DIMM);
    float var = sq * (1.f / DIMM) - mu * mu;
    float rs  = rsqrtf(var + 1e-5f);
    u16* op = out + (size_t)row * DIMM + lane * 8;
    #pragma unroll
    for (int c = 0; c < 8; c++){
        int col = lane * 8 + c;
        op[c] = f2bf((v[c] - mu) * rs * s[col] + b[col]);
    }
}

__device__ __forceinline__ float gelu_exact(float v){
    return 0.5f * v * (1.f + erff(v * 0.70710678118654752f));
}

#define LDT64 72   // padded stride for epilogue LDS scratch only

// ---------------- 128x128-tile GEMM, BK=64, dbuf + single-barrier pipeline (T3-minimal) ----------------
// LDS tiles LINEAR [128][64] u16 (gload_lds lane-contiguous dest), 2 buffers.
// Loop: stage(t+1 -> buf^1) BEFORE compute(buf); one __syncthreads per iter
// (compiler's vmcnt(0)+lgkmcnt(0) drain at the barrier provides ordering).
// MODE 0: Cout=bf16(acc); MODE 1: Cout=bf16(gelu(acc+bias)).
template<int MODE>
__global__ __launch_bounds__(256) void k_gemm128b(const u16* __restrict__ A,
                                                  const u16* __restrict__ Bt,
                                                  const float* __restrict__ bias,
                                                  u16* __restrict__ Cout,
                                                  int M, int N, int K){
    __shared__ u16 As[2][128 * 64];
    __shared__ u16 Bs[2][128 * 64];
    int m0 = blockIdx.y * 128, n0 = blockIdx.x * 128;
    int t = threadIdx.x;
    int w = t >> 6, lane = t & 63;
    int mi = lane & 15, quad = lane >> 4;
    int wr = w >> 1, wc = w & 1;

    // wave w stages rows w*32..w*32+31; one async16 covers 8 rows
    int grow = lane >> 3, gcol = (lane & 7) * 8;
    const u16* agl = A  + (size_t)(m0 + w * 32 + grow) * K + gcol;
    const u16* bgl = Bt + (size_t)(n0 + w * 32 + grow) * K + gcol;

    f32x4 acc[4][4];
    #pragma unroll
    for (int mt = 0; mt < 4; mt++)
        #pragma unroll
        for (int nt = 0; nt < 4; nt++) acc[mt][nt] = (f32x4){0.f, 0.f, 0.f, 0.f};

    int nt_k = K >> 6;
    {   // prologue: stage tile 0 -> buf 0
        u16* asl = &As[0][(w * 32) * 64];
        u16* bsl = &Bs[0][(w * 32) * 64];
        #pragma unroll
        for (int i = 0; i < 4; i++){
            async16(agl + (size_t)(i * 8) * K, asl + i * 8 * 64);
            async16(bgl + (size_t)(i * 8) * K, bsl + i * 8 * 64);
        }
    }
    __syncthreads();                           // drains vmcnt(0): buf0 ready

    for (int td = 0; td < nt_k; td++){
        int cur = td & 1;
        if (td + 1 < nt_k){                    // stage next tile BEFORE compute
            int k0 = (td + 1) << 6;
            u16* asl = &As[cur ^ 1][(w * 32) * 64];
            u16* bsl = &Bs[cur ^ 1][(w * 32) * 64];
            #pragma unroll
            for (int i = 0; i < 4; i++){
                async16(agl + (size_t)(i * 8) * K + k0, asl + i * 8 * 64);
                async16(bgl + (size_t)(i * 8) * K + k0, bsl + i * 8 * 64);
            }
        }
        const u16* Ab = &As[cur][0];
        const u16* Bb = &Bs[cur][0];
        #pragma unroll
        for (int kk = 0; kk < 64; kk += 32){
            short8 af[4], bf[4];
            #pragma unroll
            for (int mt = 0; mt < 4; mt++)
                af[mt] = *(const short8*)&Ab[(wr * 64 + mt * 16 + mi) * 64 + kk + quad * 8];
            #pragma unroll
            for (int nt = 0; nt < 4; nt++)
                bf[nt] = *(const short8*)&Bb[(wc * 64 + nt * 16 + mi) * 64 + kk + quad * 8];
            #pragma unroll
            for (int mt = 0; mt < 4; mt++)
                #pragma unroll
                for (int nt = 0; nt < 4; nt++)
                    acc[mt][nt] = __builtin_amdgcn_mfma_f32_16x16x32_bf16(af[mt], bf[nt], acc[mt][nt], 0, 0, 0);
        }
        __syncthreads();                       // my reads done + next stage drained
    }

    // ---- coalesced epilogue: per-wave C-subtile through LDS (LDT64-stride scratch over As) ----
    float bv[4];
    if (MODE == 1){
        #pragma unroll
        for (int nt = 0; nt < 4; nt++) bv[nt] = bias[n0 + wc * 64 + nt * 16 + mi];
    }
    u16* cs = ((u16*)As) + w * 16 * LDT64;     // 16x72 u16 per wave
    int erow = lane >> 2, ecol = (lane & 3) * 16;
    #pragma unroll
    for (int mt = 0; mt < 4; mt++){
        #pragma unroll
        for (int nt = 0; nt < 4; nt++)
            #pragma unroll
            for (int r = 0; r < 4; r++){
                float v = acc[mt][nt][r];
                if (MODE == 1) v = gelu_exact(v + bv[nt]);
                cs[(quad * 4 + r) * LDT64 + nt * 16 + mi] = f2bf(v);
            }
        // wave-internal write->read (DS ops in-order within a wave; compiler waits lgkmcnt)
        uint4 c0 = *(const uint4*)&cs[erow * LDT64 + ecol];
        uint4 c1 = *(const uint4*)&cs[erow * LDT64 + ecol + 8];
        u16* cp = Cout + (size_t)(m0 + wr * 64 + mt * 16 + erow) * N + n0 + wc * 64 + ecol;
        *(uint4*)cp       = c0;
        *(uint4*)(cp + 8) = c1;
    }
}

// ---------------- 64x64-tile GEMM, BK=64, dbuf single-barrier pipeline, fp32 residual RMW ----------------
__global__ __launch_bounds__(256) void k_gemm64_res(const u16* __restrict__ A,
                                                    const u16* __restrict__ Bt,
                                                    const float* __restrict__ bias,
                                                    float* __restrict__ xres,
                                                    int M, int N, int K){
    __shared__ u16 As[2][64 * 64];
    __shared__ u16 Bs[2][64 * 64];
    int m0 = blockIdx.y * 64, n0 = blockIdx.x * 64;
    int t = threadIdx.x;
    int w = t >> 6, lane = t & 63;
    int mi = lane & 15, quad = lane >> 4;

    // wave w stages rows w*16..w*16+15 (2 async16 per matrix)
    int grow = lane >> 3, gcol = (lane & 7) * 8;
    const u16* agl = A  + (size_t)(m0 + w * 16 + grow) * K + gcol;
    const u16* bgl = Bt + (size_t)(n0 + w * 16 + grow) * K + gcol;

    f32x4 acc[4];
    #pragma unroll
    for (int tt = 0; tt < 4; tt++) acc[tt] = (f32x4){0.f, 0.f, 0.f, 0.f};

    int nt_k = K >> 6;
    {   // prologue
        u16* asl = &As[0][(w * 16) * 64];
        u16* bsl = &Bs[0][(w * 16) * 64];
        #pragma unroll
        for (int i = 0; i < 2; i++){
            async16(agl + (size_t)(i * 8) * K, asl + i * 8 * 64);
            async16(bgl + (size_t)(i * 8) * K, bsl + i * 8 * 64);
        }
    }
    __syncthreads();

    for (int td = 0; td < nt_k; td++){
        int cur = td & 1;
        if (td + 1 < nt_k){
            int k0 = (td + 1) << 6;
            u16* asl = &As[cur ^ 1][(w * 16) * 64];
            u16* bsl = &Bs[cur ^ 1][(w * 16) * 64];
            #pragma unroll
            for (int i = 0; i < 2; i++){
                async16(agl + (size_t)(i * 8) * K + k0, asl + i * 8 * 64);
                async16(bgl + (size_t)(i * 8) * K + k0, bsl + i * 8 * 64);
            }
        }
        const u16* Ab = &As[cur][0];
        const u16* Bb = &Bs[cur][0];
        short8 af0 = *(const short8*)&Ab[(w * 16 + mi) * 64 + quad * 8];
        short8 af1 = *(const short8*)&Ab[(w * 16 + mi) * 64 + quad * 8 + 32];
        #pragma unroll
        for (int tt = 0; tt < 4; tt++){
            short8 bf0 = *(const short8*)&Bb[(tt * 16 + mi) * 64 + quad * 8];
            short8 bf1 = *(const short8*)&Bb[(tt * 16 + mi) * 64 + quad * 8 + 32];
            acc[tt] = __builtin_amdgcn_mfma_f32_16x16x32_bf16(af0, bf0, acc[tt], 0, 0, 0);
            acc[tt] = __builtin_amdgcn_mfma_f32_16x16x32_bf16(af1, bf1, acc[tt], 0, 0, 0);
        }
        __syncthreads();
    }

    // ---- coalesced fp32 RMW epilogue through LDS ----
    float bv[4];
    #pragma unroll
    for (int tt = 0; tt < 4; tt++) bv[tt] = bias[n0 + tt * 16 + mi];
    // per-wave 16x72 fp32 region: waves 0,1 over As (16KB), 2,3 over Bs
    float* cs = (w < 2) ? ((float*)As + w * 16 * LDT64)
                        : ((float*)Bs + (w - 2) * 16 * LDT64);
    #pragma unroll
    for (int tt = 0; tt < 4; tt++)
        #pragma unroll
        for (int r = 0; r < 4; r++)
            cs[(quad * 4 + r) * LDT64 + tt * 16 + mi] = acc[tt][r] + bv[tt];
    int erow = lane >> 2, ecol = (lane & 3) * 16;
    float* xp = xres + (size_t)(m0 + w * 16 + erow) * N + n0 + ecol;
    #pragma unroll
    for (int j = 0; j < 4; j++){
        float4 cv = *(const float4*)&cs[erow * LDT64 + ecol + j * 4];
        float4 xv = *(const float4*)(xp + j * 4);
        xv.x += cv.x; xv.y += cv.y; xv.z += cv.z; xv.w += cv.w;
        *(float4*)(xp + j * 4) = xv;
    }
}

// ---------------- MFMA flash attention (+ XCD swizzle, cvt_pk, T14 issue-early K/V loads) ----------------
#define LDK 72
#define C1_LOG2E 0.18033688011112042f   // 0.125 * log2(e)
#define C2_LOG2E 11.541560327111707f    // 8 * log2(e)

__global__ __launch_bounds__(256) void k_flash(const u16* __restrict__ qkv, u16* __restrict__ out){
    __shared__ u16 Ks[64 * LDK];        // [key][dim]
    __shared__ u16 Vt[80 * LDK];        // [dim][key]; rows 64..79 = 1.0 (l-accumulator)
    __shared__ u16 Ps[4][32 * LDK];     // per-wave P [q32][key]
    // XCD-bijective swizzle: nwg=512 -> XCD k owns batch k (8 heads x 256KB K/V = 2MB in its L2)
    int wg = (blockIdx.x & 7) * 64 + (blockIdx.x >> 3);
    int qt = wg & 7, h = (wg >> 3) & 7, b = wg >> 6;
    int t = threadIdx.x;
    int w = t >> 6, lane = t & 63;
    int mi = lane & 15, quad = lane >> 4;

    for (int i = t; i < 16 * 64; i += 256){
        int d = i >> 6, kk = i & 63;
        Vt[(64 + d) * LDK + kk] = 0x3F80;   // bf16 1.0
    }

    const u16* base = qkv + ((size_t)b * 1024) * 1536;
    int hoff = h * 64;

    short8 qf[2][2];
    #pragma unroll
    for (int qh = 0; qh < 2; qh++){
        int qrow = qt * 128 + w * 32 + qh * 16 + mi;
        const u16* qp = base + (size_t)qrow * 1536 + hoff + quad * 8;
        qf[qh][0] = *(const short8*)(qp);
        qf[qh][1] = *(const short8*)(qp + 32);
    }

    f32x4 o[2][4];
    f32x4 lacc[2];
    #pragma unroll
    for (int qh = 0; qh < 2; qh++){
        #pragma unroll
        for (int nb = 0; nb < 4; nb++) o[qh][nb] = (f32x4){0.f, 0.f, 0.f, 0.f};
        lacc[qh] = (f32x4){0.f, 0.f, 0.f, 0.f};
    }

    int kkey = t >> 2, kseg = t & 3;
    const u16* kgp = base + (size_t)kkey * 1536 + 512 + hoff + kseg * 16;
    int vkey = lane, vdg = w;
    const u16* vgp = base + (size_t)vkey * 1536 + 1024 + hoff + vdg * 16;

    // T14 prologue: issue tile-0 K/V loads
    uint4 kv0 = *(const uint4*)(kgp);
    uint4 kv1 = *(const uint4*)(kgp + 8);
    uint4 vv0 = *(const uint4*)(vgp);
    uint4 vv1 = *(const uint4*)(vgp + 8);

    for (int kt = 0; kt < 16; kt++){
        __syncthreads();                              // prev tile's LDS reads done
        *(uint4*)&Ks[kkey * LDK + kseg * 16]     = kv0;
        *(uint4*)&Ks[kkey * LDK + kseg * 16 + 8] = kv1;
        u16 vtmp[16];
        *(uint4*)&vtmp[0] = vv0;
        *(uint4*)&vtmp[8] = vv1;
        #pragma unroll
        for (int i = 0; i < 16; i++)
            Vt[(vdg * 16 + i) * LDK + vkey] = vtmp[i];   // 2 lanes/bank = free
        __syncthreads();

        if (kt < 15){                                 // issue next tile's loads: latency hides under MFMA
            size_t koff = (size_t)(kt + 1) * 64 * 1536;
            kv0 = *(const uint4*)(kgp + koff);
            kv1 = *(const uint4*)(kgp + koff + 8);
            vv0 = *(const uint4*)(vgp + koff);
            vv1 = *(const uint4*)(vgp + koff + 8);
        }

        // ---- K fragments once, shared by both q-halves ----
        short8 kb[4][2];
        #pragma unroll
        for (int nb = 0; nb < 4; nb++){
            kb[nb][0] = *(const short8*)&Ks[(nb * 16 + mi) * LDK + quad * 8];
            kb[nb][1] = *(const short8*)&Ks[(nb * 16 + mi) * LDK + quad * 8 + 32];
        }
        // ---- S = Q K^T, P = exp2(S*c1 - c2) -> LDS (packed bf16 converts) ----
        #pragma unroll
        for (int qh = 0; qh < 2; qh++){
            #pragma unroll
            for (int nb = 0; nb < 4; nb++){
                f32x4 z = (f32x4){0.f, 0.f, 0.f, 0.f};
                z = __builtin_amdgcn_mfma_f32_16x16x32_bf16(qf[qh][0], kb[nb][0], z, 0, 0, 0);
                z = __builtin_amdgcn_mfma_f32_16x16x32_bf16(qf[qh][1], kb[nb][1], z, 0, 0, 0);
                float e0 = exp2f(fmaf(z[0], C1_LOG2E, -C2_LOG2E));
                float e1 = exp2f(fmaf(z[1], C1_LOG2E, -C2_LOG2E));
                float e2 = exp2f(fmaf(z[2], C1_LOG2E, -C2_LOG2E));
                float e3 = exp2f(fmaf(z[3], C1_LOG2E, -C2_LOG2E));
                u32 p01 = cvt_pk_bf16(e0, e1);
                u32 p23 = cvt_pk_bf16(e2, e3);
                u16* pp = &Ps[w][(qh * 16 + quad * 4) * LDK + nb * 16 + mi];
                pp[0]       = (u16)p01;
                pp[LDK]     = (u16)(p01 >> 16);
                pp[2 * LDK] = (u16)p23;
                pp[3 * LDK] = (u16)(p23 >> 16);
            }
        }
        // ---- V fragments once ----
        short8 vb[4][2], lb[2];
        #pragma unroll
        for (int nb = 0; nb < 4; nb++){
            vb[nb][0] = *(const short8*)&Vt[(nb * 16 + mi) * LDK + quad * 8];
            vb[nb][1] = *(const short8*)&Vt[(nb * 16 + mi) * LDK + quad * 8 + 32];
        }
        lb[0] = *(const short8*)&Vt[(64 + mi) * LDK + quad * 8];
        lb[1] = *(const short8*)&Vt[(64 + mi) * LDK + quad * 8 + 32];
        // ---- O += P V ; l += P 1 ----
        #pragma unroll
        for (int qh = 0; qh < 2; qh++){
            const short8 a0 = *(const short8*)&Ps[w][(qh * 16 + mi) * LDK + quad * 8];
            const short8 a1 = *(const short8*)&Ps[w][(qh * 16 + mi) * LDK + quad * 8 + 32];
            #pragma unroll
            for (int nb = 0; nb < 4; nb++){
                o[qh][nb] = __builtin_amdgcn_mfma_f32_16x16x32_bf16(a0, vb[nb][0], o[qh][nb], 0, 0, 0);
                o[qh][nb] = __builtin_amdgcn_mfma_f32_16x16x32_bf16(a1, vb[nb][1], o[qh][nb], 0, 0, 0);
            }
            lacc[qh] = __builtin_amdgcn_mfma_f32_16x16x32_bf16(a0, lb[0], lacc[qh], 0, 0, 0);
            lacc[qh] = __builtin_amdgcn_mfma_f32_16x16x32_bf16(a1, lb[1], lacc[qh], 0, 0, 0);
        }
    }
    #pragma unroll
    for (int qh = 0; qh < 2; qh++){
        float invl[4];
        #pragma unroll
        for (int r = 0; r < 4; r++) invl[r] = 1.f / lacc[qh][r];
        u16* op = out + ((size_t)b * 1024 + qt * 128 + w * 32 + qh * 16) * 512 + hoff;
        #pragma unroll
        for (int nb = 0; nb < 4; nb++){
            u32 c01 = cvt_pk_bf16(o[qh][nb][0] * invl[0], o[qh][nb][1] * invl[1]);
            u32 c23 = cvt_pk_bf16(o[qh][nb][2] * invl[2], o[qh][nb][3] * invl[3]);
            u16* cp = op + (size_t)(quad * 4) * 512 + nb * 16 + mi;
            cp[0]       = (u16)c01;
            cp[512]     = (u16)(c01 >> 16);
            cp[2 * 512] = (u16)c23;
            cp[3 * 512] = (u16)(c23 >> 16);
        }
    }
}

// ---------------- host launch ----------------
extern "C" void kernel_launch(void* const* d_in, const int* in_sizes, int n_in,
                              void* d_out, int out_size, void* d_ws, size_t ws_size,
                              hipStream_t stream){
    const float* x_in  = (const float*)d_in[0];
    const float* ln1_s = (const float*)d_in[1];
    const float* ln1_b = (const float*)d_in[2];
    const float* w_qkv = (const float*)d_in[3];
    const float* w_out = (const float*)d_in[4];
    const float* b_out = (const float*)d_in[5];
    const float* ln2_s = (const float*)d_in[6];
    const float* ln2_b = (const float*)d_in[7];
    const float* w1    = (const float*)d_in[8];
    const float* b1    = (const float*)d_in[9];
    const float* w2    = (const float*)d_in[10];
    const float* b2    = (const float*)d_in[11];
    float* out = (float*)d_out;

    char* ws = (char*)d_ws;
    float* x_f32 = (float*)ws;   ws += (size_t)M_TOK * DIMM * 4;      // 16 MB fp32 residual
    u16* bufA    = (u16*)ws;     ws += (size_t)M_TOK * DIMM * 2;      // 8 MB  (ln_out / attn_out)
    u16* bufB    = (u16*)ws;     ws += (size_t)M_TOK * MLPD * 2;      // 32 MB (qkv / mlp_h)
    u16* wbase   = (u16*)ws;
    size_t per_layer_w = (size_t)(1536 + 512 + 2048 + 2048) * 512;    // 6 MB

    size_t used_big = (size_t)(ws - (char*)d_ws) + per_layer_w * 2 * DEPTH;
    bool big = (ws_size >= used_big);

    u16* ln_out   = bufA;
    u16* attn_out = bufA;
    u16* qkv      = bufB;
    u16* mlp_h    = bufB;

    size_t x_bytes = (size_t)M_TOK * DIMM * sizeof(float);
    hipMemcpyAsync(x_f32, x_in, x_bytes, hipMemcpyDeviceToDevice, stream);

    const size_t off_qkv = 0;
    const size_t off_out = (size_t)1536 * 512;
    const size_t off_w1  = off_out + (size_t)512 * 512;
    const size_t off_w2  = off_w1 + (size_t)2048 * 512;

    if (big){
        k_transpose_cvt<<<dim3(48, 16, 6), dim3(32, 8), 0, stream>>>(w_qkv, wbase + off_qkv * DEPTH, 512, 1536);
        k_transpose_cvt<<<dim3(16, 16, 6), dim3(32, 8), 0, stream>>>(w_out, wbase + off_out * DEPTH, 512, 512);
        k_transpose_cvt<<<dim3(64, 16, 6), dim3(32, 8), 0, stream>>>(w1,    wbase + off_w1  * DEPTH, 512, 2048);
        k_transpose_cvt<<<dim3(16, 64, 6), dim3(32, 8), 0, stream>>>(w2,    wbase + off_w2  * DEPTH, 2048, 512);
    }

    for (int i = 0; i < DEPTH; i++){
        u16 *wqkvT, *woutT, *w1T, *w2T;
        if (big){
            wqkvT = wbase + off_qkv * DEPTH + (size_t)i * 1536 * 512;
            woutT = wbase + off_out * DEPTH + (size_t)i * 512 * 512;
            w1T   = wbase + off_w1  * DEPTH + (size_t)i * 2048 * 512;
            w2T   = wbase + off_w2  * DEPTH + (size_t)i * 512 * 2048;
        } else {
            wqkvT = wbase + off_qkv; woutT = wbase + off_out;
            w1T   = wbase + off_w1;  w2T   = wbase + off_w2;
            k_transpose_cvt<<<dim3(48, 16), dim3(32, 8), 0, stream>>>(w_qkv + (size_t)i * 512 * 1536, wqkvT, 512, 1536);
            k_transpose_cvt<<<dim3(16, 16), dim3(32, 8), 0, stream>>>(w_out + (size_t)i * 512 * 512,  woutT, 512, 512);
            k_transpose_cvt<<<dim3(64, 16), dim3(32, 8), 0, stream>>>(w1    + (size_t)i * 512 * 2048, w1T,   512, 2048);
            k_transpose_cvt<<<dim3(16, 64), dim3(32, 8), 0, stream>>>(w2    + (size_t)i * 2048 * 512, w2T,   2048, 512);
        }

        k_layernorm<<<dim3(M_TOK / 4), dim3(256), 0, stream>>>(x_f32, ln1_s + i * 512, ln1_b + i * 512, ln_out);
        k_gemm128b<0><<<dim3(12, 64), dim3(256), 0, stream>>>(ln_out, wqkvT, nullptr, qkv,
                                                              M_TOK, 1536, 512);
        k_flash<<<dim3(512), dim3(256), 0, stream>>>(qkv, attn_out);
        k_gemm64_res<<<dim3(8, 128), dim3(256), 0, stream>>>(attn_out, woutT, b_out + i * 512, x_f32,
                                                             M_TOK, 512, 512);
        k_layernorm<<<dim3(M_TOK / 4), dim3(256), 0, stream>>>(x_f32, ln2_s + i * 512, ln2_b + i * 512, ln_out);
        k_gemm128b<1><<<dim3(16, 64), dim3(256), 0, stream>>>(ln_out, w1T, b1 + i * 2048, mlp_h,
                                                              M_TOK, 2048, 512);
        k_gemm64_res<<<dim3(8, 128), dim3(256), 0, stream>>>(mlp_h, w2T, b2 + i * 512, x_f32,
                                                             M_TOK, 512, 2048);
    }
    hipMemcpyAsync(out, x_f32, x_bytes, hipMemcpyDeviceToDevice, stream);
}

// Round 4
// 1194.772 us; speedup vs baseline: 1.5259x; 1.0574x over previous
//
#include <hip/hip_runtime.h>
#include <cstdint>
#include <cstddef>

#define M_TOK 8192
#define DIMM  512
#define HEADS 8
#define DH    64
#define MLPD  2048
#define DEPTH 6

typedef unsigned short u16;
typedef unsigned int   u32;
typedef __attribute__((ext_vector_type(8))) short short8;   // 8 bf16 (4 VGPRs)
typedef __attribute__((ext_vector_type(4))) float f32x4;    // 4 fp32 acc

__device__ __forceinline__ float bf2f(u16 u){ return __uint_as_float(((u32)u) << 16); }
__device__ __forceinline__ u16 f2bf(float f){
    u32 x = __float_as_uint(f);
    u32 r = x + 0x7fffu + ((x >> 16) & 1u);   // RNE
    return (u16)(r >> 16);
}
// packed f32x2 -> bf16x2 (RNE), 1 instr for 2 converts
__device__ __forceinline__ u32 cvt_pk_bf16(float a, float b){
    u32 r;
    asm("v_cvt_pk_bf16_f32 %0, %1, %2" : "=v"(r) : "v"(a), "v"(b));
    return r;
}
// async global->LDS, 16B per lane; lds dest must be wave-uniform base (lane*16 implicit)
__device__ __forceinline__ void async16(const u16* g, u16* l){
    __builtin_amdgcn_global_load_lds(
        (const __attribute__((address_space(1))) void*)(uintptr_t)(const void*)g,
        (__attribute__((address_space(3))) void*)(u32)(uintptr_t)(void*)l,
        16, 0, 0);
}
// XCD-grouping block swizzle: put all x-blocks sharing an A-row-panel on one XCD.
// hw linear id i -> xcd = i&7 (round-robin dispatch); bijective when nby%8==0.
__device__ __forceinline__ void xcd_swizzle(int& bx, int& by){
    int nbx = gridDim.x, nby = gridDim.y;
    if ((nby & 7) == 0){
        int i = by * nbx + bx;
        int xcd = i & 7, j = i >> 3, ypg = nby >> 3;
        int yq = j / nbx;
        by = xcd * ypg + yq;
        bx = j - yq * nbx;
    }
}

// ---------------- weight transpose + cvt: fp32 in[R][C] -> bf16 out[C][R], z layers ----------------
__global__ void k_transpose_cvt(const float* __restrict__ in, u16* __restrict__ out, int R, int C){
    __shared__ u16 tile[32][33];
    size_t zoff = (size_t)blockIdx.z * R * C;
    in += zoff; out += zoff;
    int c0 = blockIdx.x * 32, r0 = blockIdx.y * 32;
    int tx = threadIdx.x, ty = threadIdx.y;           // (32, 8)
    #pragma unroll
    for (int i = 0; i < 32; i += 8)
        tile[ty + i][tx] = f2bf(in[(size_t)(r0 + ty + i) * C + c0 + tx]);
    __syncthreads();
    #pragma unroll
    for (int i = 0; i < 32; i += 8)
        out[(size_t)(c0 + ty + i) * R + r0 + tx] = tile[tx][ty + i];
}

// ---------------- LayerNorm: fp32 x row -> bf16 out; 4 rows/block, 1 wave/row ----------------
__global__ __launch_bounds__(256) void k_layernorm(const float* __restrict__ x,
                                                   const float* __restrict__ s,
                                                   const float* __restrict__ b,
                                                   u16* __restrict__ out){
    int row = blockIdx.x * 4 + (threadIdx.x >> 6);
    int lane = threadIdx.x & 63;
    const float* xp = x + (size_t)row * DIMM + lane * 8;
    float v[8];
    #pragma unroll
    for (int c = 0; c < 8; c++) v[c] = xp[c];
    float sum = 0.f, sq = 0.f;
    #pragma unroll
    for (int c = 0; c < 8; c++){ sum += v[c]; sq += v[c] * v[c]; }
    #pragma unroll
    for (int m = 32; m >= 1; m >>= 1){
        sum += __shfl_xor(sum, m);
        sq  += __shfl_xor(sq,  m);
    }
    float mu  = sum * (1.f / DIMM);
    float var = sq * (1.f / DIMM) - mu * mu;
    float rs  = rsqrtf(var + 1e-5f);
    u16* op = out + (size_t)row * DIMM + lane * 8;
    #pragma unroll
    for (int c = 0; c < 8; c++){
        int col = lane * 8 + c;
        op[c] = f2bf((v[c] - mu) * rs * s[col] + b[col]);
    }
}

__device__ __forceinline__ float gelu_exact(float v){
    return 0.5f * v * (1.f + erff(v * 0.70710678118654752f));
}

#define LDT64 72   // padded stride for epilogue LDS scratch only

// ---------------- 128x128-tile GEMM, BK=64, dbuf + single-barrier pipeline ----------------
// LDS tiles LINEAR [128][64] u16 (gload_lds lane-contiguous dest), 2 buffers.
// MODE 0: Cout=bf16(acc); MODE 1: Cout=bf16(gelu(acc+bias)).
template<int MODE>
__global__ __launch_bounds__(256) void k_gemm128b(const u16* __restrict__ A,
                                                  const u16* __restrict__ Bt,
                                                  const float* __restrict__ bias,
                                                  u16* __restrict__ Cout,
                                                  int M, int N, int K){
    __shared__ u16 As[2][128 * 64];
    __shared__ u16 Bs[2][128 * 64];
    int bx = blockIdx.x, by = blockIdx.y;
    xcd_swizzle(bx, by);
    int m0 = by * 128, n0 = bx * 128;
    int t = threadIdx.x;
    int w = t >> 6, lane = t & 63;
    int mi = lane & 15, quad = lane >> 4;
    int wr = w >> 1, wc = w & 1;

    // wave w stages rows w*32..w*32+31; one async16 covers 8 rows
    int grow = lane >> 3, gcol = (lane & 7) * 8;
    const u16* agl = A  + (size_t)(m0 + w * 32 + grow) * K + gcol;
    const u16* bgl = Bt + (size_t)(n0 + w * 32 + grow) * K + gcol;

    f32x4 acc[4][4];
    #pragma unroll
    for (int mt = 0; mt < 4; mt++)
        #pragma unroll
        for (int nt = 0; nt < 4; nt++) acc[mt][nt] = (f32x4){0.f, 0.f, 0.f, 0.f};

    int nt_k = K >> 6;
    {   // prologue: stage tile 0 -> buf 0
        u16* asl = &As[0][(w * 32) * 64];
        u16* bsl = &Bs[0][(w * 32) * 64];
        #pragma unroll
        for (int i = 0; i < 4; i++){
            async16(agl + (size_t)(i * 8) * K, asl + i * 8 * 64);
            async16(bgl + (size_t)(i * 8) * K, bsl + i * 8 * 64);
        }
    }
    __syncthreads();                           // drains vmcnt(0): buf0 ready

    for (int td = 0; td < nt_k; td++){
        int cur = td & 1;
        if (td + 1 < nt_k){                    // stage next tile BEFORE compute
            int k0 = (td + 1) << 6;
            u16* asl = &As[cur ^ 1][(w * 32) * 64];
            u16* bsl = &Bs[cur ^ 1][(w * 32) * 64];
            #pragma unroll
            for (int i = 0; i < 4; i++){
                async16(agl + (size_t)(i * 8) * K + k0, asl + i * 8 * 64);
                async16(bgl + (size_t)(i * 8) * K + k0, bsl + i * 8 * 64);
            }
        }
        const u16* Ab = &As[cur][0];
        const u16* Bb = &Bs[cur][0];
        #pragma unroll
        for (int kk = 0; kk < 64; kk += 32){
            short8 af[4], bf[4];
            #pragma unroll
            for (int mt = 0; mt < 4; mt++)
                af[mt] = *(const short8*)&Ab[(wr * 64 + mt * 16 + mi) * 64 + kk + quad * 8];
            #pragma unroll
            for (int nt = 0; nt < 4; nt++)
                bf[nt] = *(const short8*)&Bb[(wc * 64 + nt * 16 + mi) * 64 + kk + quad * 8];
            #pragma unroll
            for (int mt = 0; mt < 4; mt++)
                #pragma unroll
                for (int nt = 0; nt < 4; nt++)
                    acc[mt][nt] = __builtin_amdgcn_mfma_f32_16x16x32_bf16(af[mt], bf[nt], acc[mt][nt], 0, 0, 0);
        }
        __syncthreads();                       // my reads done + next stage drained
    }

    // ---- coalesced epilogue: per-wave C-subtile through LDS (LDT64-stride scratch over As) ----
    float bv[4];
    if (MODE == 1){
        #pragma unroll
        for (int nt = 0; nt < 4; nt++) bv[nt] = bias[n0 + wc * 64 + nt * 16 + mi];
    }
    u16* cs = ((u16*)As) + w * 16 * LDT64;     // 16x72 u16 per wave
    int erow = lane >> 2, ecol = (lane & 3) * 16;
    #pragma unroll
    for (int mt = 0; mt < 4; mt++){
        #pragma unroll
        for (int nt = 0; nt < 4; nt++)
            #pragma unroll
            for (int r = 0; r < 4; r++){
                float v = acc[mt][nt][r];
                if (MODE == 1) v = gelu_exact(v + bv[nt]);
                cs[(quad * 4 + r) * LDT64 + nt * 16 + mi] = f2bf(v);
            }
        // wave-internal write->read (DS ops in-order within a wave; compiler waits lgkmcnt)
        uint4 c0 = *(const uint4*)&cs[erow * LDT64 + ecol];
        uint4 c1 = *(const uint4*)&cs[erow * LDT64 + ecol + 8];
        u16* cp = Cout + (size_t)(m0 + wr * 64 + mt * 16 + erow) * N + n0 + wc * 64 + ecol;
        *(uint4*)cp       = c0;
        *(uint4*)(cp + 8) = c1;
    }
}

// ---------------- 128x128-tile GEMM, BK=64, dbuf pipeline, fp32 residual RMW epilogue ----------------
// xres[m][n] += acc + bias  (each block owns a distinct tile: plain RMW, no atomics)
__global__ __launch_bounds__(256) void k_gemm128_res(const u16* __restrict__ A,
                                                     const u16* __restrict__ Bt,
                                                     const float* __restrict__ bias,
                                                     float* __restrict__ xres,
                                                     int M, int N, int K){
    __shared__ u16 As[2][128 * 64];
    __shared__ u16 Bs[2][128 * 64];
    int bx = blockIdx.x, by = blockIdx.y;
    xcd_swizzle(bx, by);
    int m0 = by * 128, n0 = bx * 128;
    int t = threadIdx.x;
    int w = t >> 6, lane = t & 63;
    int mi = lane & 15, quad = lane >> 4;
    int wr = w >> 1, wc = w & 1;

    int grow = lane >> 3, gcol = (lane & 7) * 8;
    const u16* agl = A  + (size_t)(m0 + w * 32 + grow) * K + gcol;
    const u16* bgl = Bt + (size_t)(n0 + w * 32 + grow) * K + gcol;

    f32x4 acc[4][4];
    #pragma unroll
    for (int mt = 0; mt < 4; mt++)
        #pragma unroll
        for (int nt = 0; nt < 4; nt++) acc[mt][nt] = (f32x4){0.f, 0.f, 0.f, 0.f};

    int nt_k = K >> 6;
    {   // prologue
        u16* asl = &As[0][(w * 32) * 64];
        u16* bsl = &Bs[0][(w * 32) * 64];
        #pragma unroll
        for (int i = 0; i < 4; i++){
            async16(agl + (size_t)(i * 8) * K, asl + i * 8 * 64);
            async16(bgl + (size_t)(i * 8) * K, bsl + i * 8 * 64);
        }
    }
    __syncthreads();

    for (int td = 0; td < nt_k; td++){
        int cur = td & 1;
        if (td + 1 < nt_k){
            int k0 = (td + 1) << 6;
            u16* asl = &As[cur ^ 1][(w * 32) * 64];
            u16* bsl = &Bs[cur ^ 1][(w * 32) * 64];
            #pragma unroll
            for (int i = 0; i < 4; i++){
                async16(agl + (size_t)(i * 8) * K + k0, asl + i * 8 * 64);
                async16(bgl + (size_t)(i * 8) * K + k0, bsl + i * 8 * 64);
            }
        }
        const u16* Ab = &As[cur][0];
        const u16* Bb = &Bs[cur][0];
        #pragma unroll
        for (int kk = 0; kk < 64; kk += 32){
            short8 af[4], bf[4];
            #pragma unroll
            for (int mt = 0; mt < 4; mt++)
                af[mt] = *(const short8*)&Ab[(wr * 64 + mt * 16 + mi) * 64 + kk + quad * 8];
            #pragma unroll
            for (int nt = 0; nt < 4; nt++)
                bf[nt] = *(const short8*)&Bb[(wc * 64 + nt * 16 + mi) * 64 + kk + quad * 8];
            #pragma unroll
            for (int mt = 0; mt < 4; mt++)
                #pragma unroll
                for (int nt = 0; nt < 4; nt++)
                    acc[mt][nt] = __builtin_amdgcn_mfma_f32_16x16x32_bf16(af[mt], bf[nt], acc[mt][nt], 0, 0, 0);
        }
        __syncthreads();
    }

    // ---- coalesced fp32 RMW epilogue through LDS (per-wave 16x72 fp32 region over As: 4x4.6KB=18.4KB<=32KB) ----
    float bv[4];
    #pragma unroll
    for (int nt = 0; nt < 4; nt++) bv[nt] = bias[n0 + wc * 64 + nt * 16 + mi];
    float* cs = ((float*)As) + w * 16 * LDT64;
    int erow = lane >> 2, ecol = (lane & 3) * 16;
    #pragma unroll
    for (int mt = 0; mt < 4; mt++){
        #pragma unroll
        for (int nt = 0; nt < 4; nt++)
            #pragma unroll
            for (int r = 0; r < 4; r++)
                cs[(quad * 4 + r) * LDT64 + nt * 16 + mi] = acc[mt][nt][r] + bv[nt];
        // wave-internal write->read; DS in-order within wave
        float* xp = xres + (size_t)(m0 + wr * 64 + mt * 16 + erow) * N + n0 + wc * 64 + ecol;
        #pragma unroll
        for (int j = 0; j < 4; j++){
            float4 cv = *(const float4*)&cs[erow * LDT64 + ecol + j * 4];
            float4 xv = *(const float4*)(xp + j * 4);
            xv.x += cv.x; xv.y += cv.y; xv.z += cv.z; xv.w += cv.w;
            *(float4*)(xp + j * 4) = xv;
        }
    }
}

// ---------------- MFMA flash attention (+ XCD swizzle, cvt_pk, T14 issue-early K/V loads) ----------------
#define LDK 72
#define C1_LOG2E 0.18033688011112042f   // 0.125 * log2(e)
#define C2_LOG2E 11.541560327111707f    // 8 * log2(e)

__global__ __launch_bounds__(256) void k_flash(const u16* __restrict__ qkv, u16* __restrict__ out){
    __shared__ u16 Ks[64 * LDK];        // [key][dim]
    __shared__ u16 Vt[80 * LDK];        // [dim][key]; rows 64..79 = 1.0 (l-accumulator)
    __shared__ u16 Ps[4][32 * LDK];     // per-wave P [q32][key]
    // XCD-bijective swizzle: nwg=512 -> XCD k owns batch k (8 heads x 256KB K/V = 2MB in its L2)
    int wg = (blockIdx.x & 7) * 64 + (blockIdx.x >> 3);
    int qt = wg & 7, h = (wg >> 3) & 7, b = wg >> 6;
    int t = threadIdx.x;
    int w = t >> 6, lane = t & 63;
    int mi = lane & 15, quad = lane >> 4;

    for (int i = t; i < 16 * 64; i += 256){
        int d = i >> 6, kk = i & 63;
        Vt[(64 + d) * LDK + kk] = 0x3F80;   // bf16 1.0
    }

    const u16* base = qkv + ((size_t)b * 1024) * 1536;
    int hoff = h * 64;

    short8 qf[2][2];
    #pragma unroll
    for (int qh = 0; qh < 2; qh++){
        int qrow = qt * 128 + w * 32 + qh * 16 + mi;
        const u16* qp = base + (size_t)qrow * 1536 + hoff + quad * 8;
        qf[qh][0] = *(const short8*)(qp);
        qf[qh][1] = *(const short8*)(qp + 32);
    }

    f32x4 o[2][4];
    f32x4 lacc[2];
    #pragma unroll
    for (int qh = 0; qh < 2; qh++){
        #pragma unroll
        for (int nb = 0; nb < 4; nb++) o[qh][nb] = (f32x4){0.f, 0.f, 0.f, 0.f};
        lacc[qh] = (f32x4){0.f, 0.f, 0.f, 0.f};
    }

    int kkey = t >> 2, kseg = t & 3;
    const u16* kgp = base + (size_t)kkey * 1536 + 512 + hoff + kseg * 16;
    int vkey = lane, vdg = w;
    const u16* vgp = base + (size_t)vkey * 1536 + 1024 + hoff + vdg * 16;

    // T14 prologue: issue tile-0 K/V loads
    uint4 kv0 = *(const uint4*)(kgp);
    uint4 kv1 = *(const uint4*)(kgp + 8);
    uint4 vv0 = *(const uint4*)(vgp);
    uint4 vv1 = *(const uint4*)(vgp + 8);

    for (int kt = 0; kt < 16; kt++){
        __syncthreads();                              // prev tile's LDS reads done
        *(uint4*)&Ks[kkey * LDK + kseg * 16]     = kv0;
        *(uint4*)&Ks[kkey * LDK + kseg * 16 + 8] = kv1;
        u16 vtmp[16];
        *(uint4*)&vtmp[0] = vv0;
        *(uint4*)&vtmp[8] = vv1;
        #pragma unroll
        for (int i = 0; i < 16; i++)
            Vt[(vdg * 16 + i) * LDK + vkey] = vtmp[i];   // 2 lanes/bank = free
        __syncthreads();

        if (kt < 15){                                 // issue next tile's loads: latency hides under MFMA
            size_t koff = (size_t)(kt + 1) * 64 * 1536;
            kv0 = *(const uint4*)(kgp + koff);
            kv1 = *(const uint4*)(kgp + koff + 8);
            vv0 = *(const uint4*)(vgp + koff);
            vv1 = *(const uint4*)(vgp + koff + 8);
        }

        // ---- K fragments once, shared by both q-halves ----
        short8 kb[4][2];
        #pragma unroll
        for (int nb = 0; nb < 4; nb++){
            kb[nb][0] = *(const short8*)&Ks[(nb * 16 + mi) * LDK + quad * 8];
            kb[nb][1] = *(const short8*)&Ks[(nb * 16 + mi) * LDK + quad * 8 + 32];
        }
        // ---- S = Q K^T, P = exp2(S*c1 - c2) -> LDS (packed bf16 converts) ----
        #pragma unroll
        for (int qh = 0; qh < 2; qh++){
            #pragma unroll
            for (int nb = 0; nb < 4; nb++){
                f32x4 z = (f32x4){0.f, 0.f, 0.f, 0.f};
                z = __builtin_amdgcn_mfma_f32_16x16x32_bf16(qf[qh][0], kb[nb][0], z, 0, 0, 0);
                z = __builtin_amdgcn_mfma_f32_16x16x32_bf16(qf[qh][1], kb[nb][1], z, 0, 0, 0);
                float e0 = exp2f(fmaf(z[0], C1_LOG2E, -C2_LOG2E));
                float e1 = exp2f(fmaf(z[1], C1_LOG2E, -C2_LOG2E));
                float e2 = exp2f(fmaf(z[2], C1_LOG2E, -C2_LOG2E));
                float e3 = exp2f(fmaf(z[3], C1_LOG2E, -C2_LOG2E));
                u32 p01 = cvt_pk_bf16(e0, e1);
                u32 p23 = cvt_pk_bf16(e2, e3);
                u16* pp = &Ps[w][(qh * 16 + quad * 4) * LDK + nb * 16 + mi];
                pp[0]       = (u16)p01;
                pp[LDK]     = (u16)(p01 >> 16);
                pp[2 * LDK] = (u16)p23;
                pp[3 * LDK] = (u16)(p23 >> 16);
            }
        }
        // ---- V fragments once ----
        short8 vb[4][2], lb[2];
        #pragma unroll
        for (int nb = 0; nb < 4; nb++){
            vb[nb][0] = *(const short8*)&Vt[(nb * 16 + mi) * LDK + quad * 8];
            vb[nb][1] = *(const short8*)&Vt[(nb * 16 + mi) * LDK + quad * 8 + 32];
        }
        lb[0] = *(const short8*)&Vt[(64 + mi) * LDK + quad * 8];
        lb[1] = *(const short8*)&Vt[(64 + mi) * LDK + quad * 8 + 32];
        // ---- O += P V ; l += P 1 ----
        #pragma unroll
        for (int qh = 0; qh < 2; qh++){
            const short8 a0 = *(const short8*)&Ps[w][(qh * 16 + mi) * LDK + quad * 8];
            const short8 a1 = *(const short8*)&Ps[w][(qh * 16 + mi) * LDK + quad * 8 + 32];
            #pragma unroll
            for (int nb = 0; nb < 4; nb++){
                o[qh][nb] = __builtin_amdgcn_mfma_f32_16x16x32_bf16(a0, vb[nb][0], o[qh][nb], 0, 0, 0);
                o[qh][nb] = __builtin_amdgcn_mfma_f32_16x16x32_bf16(a1, vb[nb][1], o[qh][nb], 0, 0, 0);
            }
            lacc[qh] = __builtin_amdgcn_mfma_f32_16x16x32_bf16(a0, lb[0], lacc[qh], 0, 0, 0);
            lacc[qh] = __builtin_amdgcn_mfma_f32_16x16x32_bf16(a1, lb[1], lacc[qh], 0, 0, 0);
        }
    }
    #pragma unroll
    for (int qh = 0; qh < 2; qh++){
        float invl[4];
        #pragma unroll
        for (int r = 0; r < 4; r++) invl[r] = 1.f / lacc[qh][r];
        u16* op = out + ((size_t)b * 1024 + qt * 128 + w * 32 + qh * 16) * 512 + hoff;
        #pragma unroll
        for (int nb = 0; nb < 4; nb++){
            u32 c01 = cvt_pk_bf16(o[qh][nb][0] * invl[0], o[qh][nb][1] * invl[1]);
            u32 c23 = cvt_pk_bf16(o[qh][nb][2] * invl[2], o[qh][nb][3] * invl[3]);
            u16* cp = op + (size_t)(quad * 4) * 512 + nb * 16 + mi;
            cp[0]       = (u16)c01;
            cp[512]     = (u16)(c01 >> 16);
            cp[2 * 512] = (u16)c23;
            cp[3 * 512] = (u16)(c23 >> 16);
        }
    }
}

// ---------------- host launch ----------------
extern "C" void kernel_launch(void* const* d_in, const int* in_sizes, int n_in,
                              void* d_out, int out_size, void* d_ws, size_t ws_size,
                              hipStream_t stream){
    const float* x_in  = (const float*)d_in[0];
    const float* ln1_s = (const float*)d_in[1];
    const float* ln1_b = (const float*)d_in[2];
    const float* w_qkv = (const float*)d_in[3];
    const float* w_out = (const float*)d_in[4];
    const float* b_out = (const float*)d_in[5];
    const float* ln2_s = (const float*)d_in[6];
    const float* ln2_b = (const float*)d_in[7];
    const float* w1    = (const float*)d_in[8];
    const float* b1    = (const float*)d_in[9];
    const float* w2    = (const float*)d_in[10];
    const float* b2    = (const float*)d_in[11];
    float* out = (float*)d_out;

    char* ws = (char*)d_ws;
    float* x_f32 = (float*)ws;   ws += (size_t)M_TOK * DIMM * 4;      // 16 MB fp32 residual
    u16* bufA    = (u16*)ws;     ws += (size_t)M_TOK * DIMM * 2;      // 8 MB  (ln_out / attn_out)
    u16* bufB    = (u16*)ws;     ws += (size_t)M_TOK * MLPD * 2;      // 32 MB (qkv / mlp_h)
    u16* wbase   = (u16*)ws;
    size_t per_layer_w = (size_t)(1536 + 512 + 2048 + 2048) * 512;    // 6 MB

    size_t used_big = (size_t)(ws - (char*)d_ws) + per_layer_w * 2 * DEPTH;
    bool big = (ws_size >= used_big);

    u16* ln_out   = bufA;
    u16* attn_out = bufA;
    u16* qkv      = bufB;
    u16* mlp_h    = bufB;

    size_t x_bytes = (size_t)M_TOK * DIMM * sizeof(float);
    hipMemcpyAsync(x_f32, x_in, x_bytes, hipMemcpyDeviceToDevice, stream);

    const size_t off_qkv = 0;
    const size_t off_out = (size_t)1536 * 512;
    const size_t off_w1  = off_out + (size_t)512 * 512;
    const size_t off_w2  = off_w1 + (size_t)2048 * 512;

    if (big){
        k_transpose_cvt<<<dim3(48, 16, 6), dim3(32, 8), 0, stream>>>(w_qkv, wbase + off_qkv * DEPTH, 512, 1536);
        k_transpose_cvt<<<dim3(16, 16, 6), dim3(32, 8), 0, stream>>>(w_out, wbase + off_out * DEPTH, 512, 512);
        k_transpose_cvt<<<dim3(64, 16, 6), dim3(32, 8), 0, stream>>>(w1,    wbase + off_w1  * DEPTH, 512, 2048);
        k_transpose_cvt<<<dim3(16, 64, 6), dim3(32, 8), 0, stream>>>(w2,    wbase + off_w2  * DEPTH, 2048, 512);
    }

    for (int i = 0; i < DEPTH; i++){
        u16 *wqkvT, *woutT, *w1T, *w2T;
        if (big){
            wqkvT = wbase + off_qkv * DEPTH + (size_t)i * 1536 * 512;
            woutT = wbase + off_out * DEPTH + (size_t)i * 512 * 512;
            w1T   = wbase + off_w1  * DEPTH + (size_t)i * 2048 * 512;
            w2T   = wbase + off_w2  * DEPTH + (size_t)i * 512 * 2048;
        } else {
            wqkvT = wbase + off_qkv; woutT = wbase + off_out;
            w1T   = wbase + off_w1;  w2T   = wbase + off_w2;
            k_transpose_cvt<<<dim3(48, 16), dim3(32, 8), 0, stream>>>(w_qkv + (size_t)i * 512 * 1536, wqkvT, 512, 1536);
            k_transpose_cvt<<<dim3(16, 16), dim3(32, 8), 0, stream>>>(w_out + (size_t)i * 512 * 512,  woutT, 512, 512);
            k_transpose_cvt<<<dim3(64, 16), dim3(32, 8), 0, stream>>>(w1    + (size_t)i * 512 * 2048, w1T,   512, 2048);
            k_transpose_cvt<<<dim3(16, 64), dim3(32, 8), 0, stream>>>(w2    + (size_t)i * 2048 * 512, w2T,   2048, 512);
        }

        k_layernorm<<<dim3(M_TOK / 4), dim3(256), 0, stream>>>(x_f32, ln1_s + i * 512, ln1_b + i * 512, ln_out);
        k_gemm128b<0><<<dim3(12, 64), dim3(256), 0, stream>>>(ln_out, wqkvT, nullptr, qkv,
                                                              M_TOK, 1536, 512);
        k_flash<<<dim3(512), dim3(256), 0, stream>>>(qkv, attn_out);
        k_gemm128_res<<<dim3(4, 64), dim3(256), 0, stream>>>(attn_out, woutT, b_out + i * 512, x_f32,
                                                             M_TOK, 512, 512);
        k_layernorm<<<dim3(M_TOK / 4), dim3(256), 0, stream>>>(x_f32, ln2_s + i * 512, ln2_b + i * 512, ln_out);
        k_gemm128b<1><<<dim3(16, 64), dim3(256), 0, stream>>>(ln_out, w1T, b1 + i * 2048, mlp_h,
                                                              M_TOK, 2048, 512);
        k_gemm128_res<<<dim3(4, 64), dim3(256), 0, stream>>>(mlp_h, w2T, b2 + i * 512, x_f32,
                                                             M_TOK, 512, 2048);
    }
    hipMemcpyAsync(out, x_f32, x_bytes, hipMemcpyDeviceToDevice, stream);
}

// Round 5
// 1152.654 us; speedup vs baseline: 1.5816x; 1.0365x over previous
//
#include <hip/hip_runtime.h>
#include <cstdint>
#include <cstddef>

#define M_TOK 8192
#define DIMM  512
#define HEADS 8
#define DH    64
#define MLPD  2048
#define DEPTH 6

typedef unsigned short u16;
typedef unsigned int   u32;
typedef __attribute__((ext_vector_type(8))) short short8;   // 8 bf16 (4 VGPRs)
typedef __attribute__((ext_vector_type(4))) float f32x4;    // 4 fp32 acc

__device__ __forceinline__ float bf2f(u16 u){ return __uint_as_float(((u32)u) << 16); }
__device__ __forceinline__ u16 f2bf(float f){
    u32 x = __float_as_uint(f);
    u32 r = x + 0x7fffu + ((x >> 16) & 1u);   // RNE
    return (u16)(r >> 16);
}
// packed f32x2 -> bf16x2 (RNE), 1 instr for 2 converts
__device__ __forceinline__ u32 cvt_pk_bf16(float a, float b){
    u32 r;
    asm("v_cvt_pk_bf16_f32 %0, %1, %2" : "=v"(r) : "v"(a), "v"(b));
    return r;
}
// async global->LDS, 16B per lane; lds dest must be wave-uniform base (lane*16 implicit)
__device__ __forceinline__ void async16(const u16* g, u16* l){
    __builtin_amdgcn_global_load_lds(
        (const __attribute__((address_space(1))) void*)(uintptr_t)(const void*)g,
        (__attribute__((address_space(3))) void*)(u32)(uintptr_t)(void*)l,
        16, 0, 0);
}
// XCD-grouping block swizzle: put all x-blocks sharing an A-row-panel on one XCD.
// hw linear id i -> xcd = i&7 (round-robin dispatch); bijective when nby%8==0.
__device__ __forceinline__ void xcd_swizzle(int& bx, int& by){
    int nbx = gridDim.x, nby = gridDim.y;
    if ((nby & 7) == 0){
        int i = by * nbx + bx;
        int xcd = i & 7, j = i >> 3, ypg = nby >> 3;
        int yq = j / nbx;
        by = xcd * ypg + yq;
        bx = j - yq * nbx;
    }
}

// ---------------- weight transpose + cvt: fp32 in[R][C] -> bf16 out[C][R], z layers ----------------
__global__ void k_transpose_cvt(const float* __restrict__ in, u16* __restrict__ out, int R, int C){
    __shared__ u16 tile[32][33];
    size_t zoff = (size_t)blockIdx.z * R * C;
    in += zoff; out += zoff;
    int c0 = blockIdx.x * 32, r0 = blockIdx.y * 32;
    int tx = threadIdx.x, ty = threadIdx.y;           // (32, 8)
    #pragma unroll
    for (int i = 0; i < 32; i += 8)
        tile[ty + i][tx] = f2bf(in[(size_t)(r0 + ty + i) * C + c0 + tx]);
    __syncthreads();
    #pragma unroll
    for (int i = 0; i < 32; i += 8)
        out[(size_t)(c0 + ty + i) * R + r0 + tx] = tile[tx][ty + i];
}

// ---------------- LayerNorm: fp32 x row -> bf16 out; 4 rows/block, 1 wave/row ----------------
__global__ __launch_bounds__(256) void k_layernorm(const float* __restrict__ x,
                                                   const float* __restrict__ s,
                                                   const float* __restrict__ b,
                                                   u16* __restrict__ out){
    int row = blockIdx.x * 4 + (threadIdx.x >> 6);
    int lane = threadIdx.x & 63;
    const float* xp = x + (size_t)row * DIMM + lane * 8;
    float v[8];
    #pragma unroll
    for (int c = 0; c < 8; c++) v[c] = xp[c];
    float sum = 0.f, sq = 0.f;
    #pragma unroll
    for (int c = 0; c < 8; c++){ sum += v[c]; sq += v[c] * v[c]; }
    #pragma unroll
    for (int m = 32; m >= 1; m >>= 1){
        sum += __shfl_xor(sum, m);
        sq  += __shfl_xor(sq,  m);
    }
    float mu  = sum * (1.f / DIMM);
    float var = sq * (1.f / DIMM) - mu * mu;
    float rs  = rsqrtf(var + 1e-5f);
    u16* op = out + (size_t)row * DIMM + lane * 8;
    #pragma unroll
    for (int c = 0; c < 8; c++){
        int col = lane * 8 + c;
        op[c] = f2bf((v[c] - mu) * rs * s[col] + b[col]);
    }
}

// Abramowitz-Stegun 7.1.26 erf (abs err 1.5e-7): rcp + 5 FMA + exp2, no branches.
__device__ __forceinline__ float erf_as(float x){
    float ax = fabsf(x);
    float t  = __builtin_amdgcn_rcpf(fmaf(0.3275911f, ax, 1.f));
    float y  = fmaf(fmaf(fmaf(fmaf(1.061405429f, t, -1.453152027f), t,
                              1.421413741f), t, -0.284496736f), t, 0.254829592f) * t;
    float e  = exp2f(-ax * ax * 1.4426950408889634f);
    float r  = 1.f - y * e;
    return copysignf(r, x);
}
__device__ __forceinline__ float gelu_exact(float v){
    return 0.5f * v * (1.f + erf_as(v * 0.70710678118654752f));
}

#define LDT64 72   // padded stride for epilogue LDS scratch only

// ---------------- 128x128-tile GEMM, BK=64, dbuf + single-barrier pipeline ----------------
// LDS tiles LINEAR [128][64] u16 (gload_lds lane-contiguous dest), 2 buffers.
// MODE 0: Cout=bf16(acc); MODE 1: Cout=bf16(gelu(acc+bias)).
template<int MODE>
__global__ __launch_bounds__(256) void k_gemm128b(const u16* __restrict__ A,
                                                  const u16* __restrict__ Bt,
                                                  const float* __restrict__ bias,
                                                  u16* __restrict__ Cout,
                                                  int M, int N, int K){
    __shared__ u16 As[2][128 * 64];
    __shared__ u16 Bs[2][128 * 64];
    int bx = blockIdx.x, by = blockIdx.y;
    xcd_swizzle(bx, by);
    int m0 = by * 128, n0 = bx * 128;
    int t = threadIdx.x;
    int w = t >> 6, lane = t & 63;
    int mi = lane & 15, quad = lane >> 4;
    int wr = w >> 1, wc = w & 1;

    // wave w stages rows w*32..w*32+31; one async16 covers 8 rows
    int grow = lane >> 3, gcol = (lane & 7) * 8;
    const u16* agl = A  + (size_t)(m0 + w * 32 + grow) * K + gcol;
    const u16* bgl = Bt + (size_t)(n0 + w * 32 + grow) * K + gcol;

    f32x4 acc[4][4];
    #pragma unroll
    for (int mt = 0; mt < 4; mt++)
        #pragma unroll
        for (int nt = 0; nt < 4; nt++) acc[mt][nt] = (f32x4){0.f, 0.f, 0.f, 0.f};

    int nt_k = K >> 6;
    {   // prologue: stage tile 0 -> buf 0
        u16* asl = &As[0][(w * 32) * 64];
        u16* bsl = &Bs[0][(w * 32) * 64];
        #pragma unroll
        for (int i = 0; i < 4; i++){
            async16(agl + (size_t)(i * 8) * K, asl + i * 8 * 64);
            async16(bgl + (size_t)(i * 8) * K, bsl + i * 8 * 64);
        }
    }
    __syncthreads();                           // drains vmcnt(0): buf0 ready

    for (int td = 0; td < nt_k; td++){
        int cur = td & 1;
        if (td + 1 < nt_k){                    // stage next tile BEFORE compute
            int k0 = (td + 1) << 6;
            u16* asl = &As[cur ^ 1][(w * 32) * 64];
            u16* bsl = &Bs[cur ^ 1][(w * 32) * 64];
            #pragma unroll
            for (int i = 0; i < 4; i++){
                async16(agl + (size_t)(i * 8) * K + k0, asl + i * 8 * 64);
                async16(bgl + (size_t)(i * 8) * K + k0, bsl + i * 8 * 64);
            }
        }
        const u16* Ab = &As[cur][0];
        const u16* Bb = &Bs[cur][0];
        #pragma unroll
        for (int kk = 0; kk < 64; kk += 32){
            short8 af[4], bf[4];
            #pragma unroll
            for (int mt = 0; mt < 4; mt++)
                af[mt] = *(const short8*)&Ab[(wr * 64 + mt * 16 + mi) * 64 + kk + quad * 8];
            #pragma unroll
            for (int nt = 0; nt < 4; nt++)
                bf[nt] = *(const short8*)&Bb[(wc * 64 + nt * 16 + mi) * 64 + kk + quad * 8];
            #pragma unroll
            for (int mt = 0; mt < 4; mt++)
                #pragma unroll
                for (int nt = 0; nt < 4; nt++)
                    acc[mt][nt] = __builtin_amdgcn_mfma_f32_16x16x32_bf16(af[mt], bf[nt], acc[mt][nt], 0, 0, 0);
        }
        __syncthreads();                       // my reads done + next stage drained
    }

    // ---- coalesced epilogue: per-wave C-subtile through LDS (LDT64-stride scratch over As) ----
    float bv[4];
    if (MODE == 1){
        #pragma unroll
        for (int nt = 0; nt < 4; nt++) bv[nt] = bias[n0 + wc * 64 + nt * 16 + mi];
    }
    u16* cs = ((u16*)As) + w * 16 * LDT64;     // 16x72 u16 per wave
    int erow = lane >> 2, ecol = (lane & 3) * 16;
    #pragma unroll
    for (int mt = 0; mt < 4; mt++){
        #pragma unroll
        for (int nt = 0; nt < 4; nt++)
            #pragma unroll
            for (int r = 0; r < 4; r++){
                float v = acc[mt][nt][r];
                if (MODE == 1) v = gelu_exact(v + bv[nt]);
                cs[(quad * 4 + r) * LDT64 + nt * 16 + mi] = f2bf(v);
            }
        // wave-internal write->read (DS ops in-order within a wave; compiler waits lgkmcnt)
        uint4 c0 = *(const uint4*)&cs[erow * LDT64 + ecol];
        uint4 c1 = *(const uint4*)&cs[erow * LDT64 + ecol + 8];
        u16* cp = Cout + (size_t)(m0 + wr * 64 + mt * 16 + erow) * N + n0 + wc * 64 + ecol;
        *(uint4*)cp       = c0;
        *(uint4*)(cp + 8) = c1;
    }
}

// ---------------- 128x128-tile GEMM, BK=64, dbuf pipeline, fp32 residual RMW epilogue ----------------
// xres[m][n] += acc + bias  (each block owns a distinct tile: plain RMW, no atomics)
__global__ __launch_bounds__(256) void k_gemm128_res(const u16* __restrict__ A,
                                                     const u16* __restrict__ Bt,
                                                     const float* __restrict__ bias,
                                                     float* __restrict__ xres,
                                                     int M, int N, int K){
    __shared__ u16 As[2][128 * 64];
    __shared__ u16 Bs[2][128 * 64];
    int bx = blockIdx.x, by = blockIdx.y;
    xcd_swizzle(bx, by);
    int m0 = by * 128, n0 = bx * 128;
    int t = threadIdx.x;
    int w = t >> 6, lane = t & 63;
    int mi = lane & 15, quad = lane >> 4;
    int wr = w >> 1, wc = w & 1;

    int grow = lane >> 3, gcol = (lane & 7) * 8;
    const u16* agl = A  + (size_t)(m0 + w * 32 + grow) * K + gcol;
    const u16* bgl = Bt + (size_t)(n0 + w * 32 + grow) * K + gcol;

    f32x4 acc[4][4];
    #pragma unroll
    for (int mt = 0; mt < 4; mt++)
        #pragma unroll
        for (int nt = 0; nt < 4; nt++) acc[mt][nt] = (f32x4){0.f, 0.f, 0.f, 0.f};

    int nt_k = K >> 6;
    {   // prologue
        u16* asl = &As[0][(w * 32) * 64];
        u16* bsl = &Bs[0][(w * 32) * 64];
        #pragma unroll
        for (int i = 0; i < 4; i++){
            async16(agl + (size_t)(i * 8) * K, asl + i * 8 * 64);
            async16(bgl + (size_t)(i * 8) * K, bsl + i * 8 * 64);
        }
    }
    __syncthreads();

    for (int td = 0; td < nt_k; td++){
        int cur = td & 1;
        if (td + 1 < nt_k){
            int k0 = (td + 1) << 6;
            u16* asl = &As[cur ^ 1][(w * 32) * 64];
            u16* bsl = &Bs[cur ^ 1][(w * 32) * 64];
            #pragma unroll
            for (int i = 0; i < 4; i++){
                async16(agl + (size_t)(i * 8) * K + k0, asl + i * 8 * 64);
                async16(bgl + (size_t)(i * 8) * K + k0, bsl + i * 8 * 64);
            }
        }
        const u16* Ab = &As[cur][0];
        const u16* Bb = &Bs[cur][0];
        #pragma unroll
        for (int kk = 0; kk < 64; kk += 32){
            short8 af[4], bf[4];
            #pragma unroll
            for (int mt = 0; mt < 4; mt++)
                af[mt] = *(const short8*)&Ab[(wr * 64 + mt * 16 + mi) * 64 + kk + quad * 8];
            #pragma unroll
            for (int nt = 0; nt < 4; nt++)
                bf[nt] = *(const short8*)&Bb[(wc * 64 + nt * 16 + mi) * 64 + kk + quad * 8];
            #pragma unroll
            for (int mt = 0; mt < 4; mt++)
                #pragma unroll
                for (int nt = 0; nt < 4; nt++)
                    acc[mt][nt] = __builtin_amdgcn_mfma_f32_16x16x32_bf16(af[mt], bf[nt], acc[mt][nt], 0, 0, 0);
        }
        __syncthreads();
    }

    // ---- coalesced fp32 RMW epilogue through LDS (per-wave 16x72 fp32 region over As) ----
    float bv[4];
    #pragma unroll
    for (int nt = 0; nt < 4; nt++) bv[nt] = bias[n0 + wc * 64 + nt * 16 + mi];
    float* cs = ((float*)As) + w * 16 * LDT64;
    int erow = lane >> 2, ecol = (lane & 3) * 16;
    #pragma unroll
    for (int mt = 0; mt < 4; mt++){
        #pragma unroll
        for (int nt = 0; nt < 4; nt++)
            #pragma unroll
            for (int r = 0; r < 4; r++)
                cs[(quad * 4 + r) * LDT64 + nt * 16 + mi] = acc[mt][nt][r] + bv[nt];
        // wave-internal write->read; DS in-order within wave
        float* xp = xres + (size_t)(m0 + wr * 64 + mt * 16 + erow) * N + n0 + wc * 64 + ecol;
        #pragma unroll
        for (int j = 0; j < 4; j++){
            float4 cv = *(const float4*)&cs[erow * LDT64 + ecol + j * 4];
            float4 xv = *(const float4*)(xp + j * 4);
            xv.x += cv.x; xv.y += cv.y; xv.z += cv.z; xv.w += cv.w;
            *(float4*)(xp + j * 4) = xv;
        }
    }
}

// ---------------- MFMA flash attention ----------------
#define LDK 72
#define C1_LOG2E 0.18033688011112042f   // 0.125 * log2(e)
#define C2_LOG2E 11.541560327111707f    // 8 * log2(e)
#define OSPLIT (M_TOK * 512)            // floats per split O buffer
#define LSPLIT (M_TOK * 8)              // floats per split l buffer

// split-K flash: grid 1024 (2 splits x 512); fixed-max softmax => partials combine exactly.
// Writes fp32 partial O (pre-division) and l to workspace.
__global__ __launch_bounds__(256) void k_flash_split(const u16* __restrict__ qkv,
                                                     float* __restrict__ Opart,
                                                     float* __restrict__ lpart){
    __shared__ u16 Ks[64 * LDK];        // [key][dim]
    __shared__ u16 Vt[80 * LDK];        // [dim][key]; rows 64..79 = 1.0 (l-accumulator)
    __shared__ u16 Ps[4][32 * LDK];     // per-wave P [q32][key]
    // XCD swizzle: nwg=1024, cpx=128 -> XCD k owns batch k (both splits co-located)
    int wg = (blockIdx.x & 7) * 128 + (blockIdx.x >> 3);
    int qt = wg & 7, h = (wg >> 3) & 7, sp = (wg >> 6) & 1, b = wg >> 7;
    int t = threadIdx.x;
    int w = t >> 6, lane = t & 63;
    int mi = lane & 15, quad = lane >> 4;

    for (int i = t; i < 16 * 64; i += 256){
        int d = i >> 6, kk = i & 63;
        Vt[(64 + d) * LDK + kk] = 0x3F80;   // bf16 1.0
    }

    const u16* base = qkv + ((size_t)b * 1024) * 1536;
    int hoff = h * 64;

    short8 qf[2][2];
    #pragma unroll
    for (int qh = 0; qh < 2; qh++){
        int qrow = qt * 128 + w * 32 + qh * 16 + mi;
        const u16* qp = base + (size_t)qrow * 1536 + hoff + quad * 8;
        qf[qh][0] = *(const short8*)(qp);
        qf[qh][1] = *(const short8*)(qp + 32);
    }

    f32x4 o[2][4];
    f32x4 lacc[2];
    #pragma unroll
    for (int qh = 0; qh < 2; qh++){
        #pragma unroll
        for (int nb = 0; nb < 4; nb++) o[qh][nb] = (f32x4){0.f, 0.f, 0.f, 0.f};
        lacc[qh] = (f32x4){0.f, 0.f, 0.f, 0.f};
    }

    int kkey = t >> 2, kseg = t & 3;
    const u16* kgp = base + (size_t)kkey * 1536 + 512 + hoff + kseg * 16;
    int vkey = lane, vdg = w;
    const u16* vgp = base + (size_t)vkey * 1536 + 1024 + hoff + vdg * 16;

    int kt0 = sp * 8;
    // T14 prologue: issue first-tile K/V loads
    size_t koff0 = (size_t)kt0 * 64 * 1536;
    uint4 kv0 = *(const uint4*)(kgp + koff0);
    uint4 kv1 = *(const uint4*)(kgp + koff0 + 8);
    uint4 vv0 = *(const uint4*)(vgp + koff0);
    uint4 vv1 = *(const uint4*)(vgp + koff0 + 8);

    for (int kt = kt0; kt < kt0 + 8; kt++){
        __syncthreads();                              // prev tile's LDS reads done
        *(uint4*)&Ks[kkey * LDK + kseg * 16]     = kv0;
        *(uint4*)&Ks[kkey * LDK + kseg * 16 + 8] = kv1;
        u16 vtmp[16];
        *(uint4*)&vtmp[0] = vv0;
        *(uint4*)&vtmp[8] = vv1;
        #pragma unroll
        for (int i = 0; i < 16; i++)
            Vt[(vdg * 16 + i) * LDK + vkey] = vtmp[i];   // 2 lanes/bank = free
        __syncthreads();

        if (kt < kt0 + 7){                            // issue next tile's loads under MFMA
            size_t koff = (size_t)(kt + 1) * 64 * 1536;
            kv0 = *(const uint4*)(kgp + koff);
            kv1 = *(const uint4*)(kgp + koff + 8);
            vv0 = *(const uint4*)(vgp + koff);
            vv1 = *(const uint4*)(vgp + koff + 8);
        }

        // ---- K fragments once, shared by both q-halves ----
        short8 kb[4][2];
        #pragma unroll
        for (int nb = 0; nb < 4; nb++){
            kb[nb][0] = *(const short8*)&Ks[(nb * 16 + mi) * LDK + quad * 8];
            kb[nb][1] = *(const short8*)&Ks[(nb * 16 + mi) * LDK + quad * 8 + 32];
        }
        // ---- S = Q K^T, P = exp2(S*c1 - c2) -> LDS (packed bf16 converts) ----
        #pragma unroll
        for (int qh = 0; qh < 2; qh++){
            #pragma unroll
            for (int nb = 0; nb < 4; nb++){
                f32x4 z = (f32x4){0.f, 0.f, 0.f, 0.f};
                z = __builtin_amdgcn_mfma_f32_16x16x32_bf16(qf[qh][0], kb[nb][0], z, 0, 0, 0);
                z = __builtin_amdgcn_mfma_f32_16x16x32_bf16(qf[qh][1], kb[nb][1], z, 0, 0, 0);
                float e0 = exp2f(fmaf(z[0], C1_LOG2E, -C2_LOG2E));
                float e1 = exp2f(fmaf(z[1], C1_LOG2E, -C2_LOG2E));
                float e2 = exp2f(fmaf(z[2], C1_LOG2E, -C2_LOG2E));
                float e3 = exp2f(fmaf(z[3], C1_LOG2E, -C2_LOG2E));
                u32 p01 = cvt_pk_bf16(e0, e1);
                u32 p23 = cvt_pk_bf16(e2, e3);
                u16* pp = &Ps[w][(qh * 16 + quad * 4) * LDK + nb * 16 + mi];
                pp[0]       = (u16)p01;
                pp[LDK]     = (u16)(p01 >> 16);
                pp[2 * LDK] = (u16)p23;
                pp[3 * LDK] = (u16)(p23 >> 16);
            }
        }
        // ---- V fragments once ----
        short8 vb[4][2], lb[2];
        #pragma unroll
        for (int nb = 0; nb < 4; nb++){
            vb[nb][0] = *(const short8*)&Vt[(nb * 16 + mi) * LDK + quad * 8];
            vb[nb][1] = *(const short8*)&Vt[(nb * 16 + mi) * LDK + quad * 8 + 32];
        }
        lb[0] = *(const short8*)&Vt[(64 + mi) * LDK + quad * 8];
        lb[1] = *(const short8*)&Vt[(64 + mi) * LDK + quad * 8 + 32];
        // ---- O += P V ; l += P 1 ----
        #pragma unroll
        for (int qh = 0; qh < 2; qh++){
            const short8 a0 = *(const short8*)&Ps[w][(qh * 16 + mi) * LDK + quad * 8];
            const short8 a1 = *(const short8*)&Ps[w][(qh * 16 + mi) * LDK + quad * 8 + 32];
            #pragma unroll
            for (int nb = 0; nb < 4; nb++){
                o[qh][nb] = __builtin_amdgcn_mfma_f32_16x16x32_bf16(a0, vb[nb][0], o[qh][nb], 0, 0, 0);
                o[qh][nb] = __builtin_amdgcn_mfma_f32_16x16x32_bf16(a1, vb[nb][1], o[qh][nb], 0, 0, 0);
            }
            lacc[qh] = __builtin_amdgcn_mfma_f32_16x16x32_bf16(a0, lb[0], lacc[qh], 0, 0, 0);
            lacc[qh] = __builtin_amdgcn_mfma_f32_16x16x32_bf16(a1, lb[1], lacc[qh], 0, 0, 0);
        }
    }
    // ---- fp32 partial epilogue ----
    float* Ob = Opart + (size_t)sp * OSPLIT;
    float* lb2 = lpart + (size_t)sp * LSPLIT;
    #pragma unroll
    for (int qh = 0; qh < 2; qh++){
        int grow0 = b * 1024 + qt * 128 + w * 32 + qh * 16;
        float* op = Ob + (size_t)grow0 * 512 + hoff;
        #pragma unroll
        for (int nb = 0; nb < 4; nb++)
            #pragma unroll
            for (int r = 0; r < 4; r++)
                op[(size_t)(quad * 4 + r) * 512 + nb * 16 + mi] = o[qh][nb][r];
        if (mi == 0){
            #pragma unroll
            for (int r = 0; r < 4; r++)
                lb2[(size_t)(grow0 + quad * 4 + r) * 8 + h] = lacc[qh][r];
        }
    }
}

// combine: out = bf16((O0+O1)/(l0+l1)); 8 elems/thread, fully coalesced
__global__ __launch_bounds__(256) void k_combine(const float* __restrict__ Opart,
                                                 const float* __restrict__ lpart,
                                                 u16* __restrict__ out){
    int tid = blockIdx.x * 256 + threadIdx.x;
    size_t basei = (size_t)tid * 8;
    int row = (int)(basei >> 9), col = (int)(basei & 511), h = col >> 6;
    float l = lpart[(size_t)row * 8 + h] + lpart[(size_t)LSPLIT + (size_t)row * 8 + h];
    float inv = 1.f / l;
    float4 a0 = *(const float4*)(Opart + basei);
    float4 a1 = *(const float4*)(Opart + basei + 4);
    float4 b0 = *(const float4*)(Opart + (size_t)OSPLIT + basei);
    float4 b1 = *(const float4*)(Opart + (size_t)OSPLIT + basei + 4);
    uint4 r;
    r.x = cvt_pk_bf16((a0.x + b0.x) * inv, (a0.y + b0.y) * inv);
    r.y = cvt_pk_bf16((a0.z + b0.z) * inv, (a0.w + b0.w) * inv);
    r.z = cvt_pk_bf16((a1.x + b1.x) * inv, (a1.y + b1.y) * inv);
    r.w = cvt_pk_bf16((a1.z + b1.z) * inv, (a1.w + b1.w) * inv);
    *(uint4*)(out + basei) = r;
}

// fallback single-pass flash (round-4 verified), used when workspace too small for partials
__global__ __launch_bounds__(256) void k_flash(const u16* __restrict__ qkv, u16* __restrict__ out){
    __shared__ u16 Ks[64 * LDK];
    __shared__ u16 Vt[80 * LDK];
    __shared__ u16 Ps[4][32 * LDK];
    int wg = (blockIdx.x & 7) * 64 + (blockIdx.x >> 3);
    int qt = wg & 7, h = (wg >> 3) & 7, b = wg >> 6;
    int t = threadIdx.x;
    int w = t >> 6, lane = t & 63;
    int mi = lane & 15, quad = lane >> 4;

    for (int i = t; i < 16 * 64; i += 256){
        int d = i >> 6, kk = i & 63;
        Vt[(64 + d) * LDK + kk] = 0x3F80;
    }
    const u16* base = qkv + ((size_t)b * 1024) * 1536;
    int hoff = h * 64;

    short8 qf[2][2];
    #pragma unroll
    for (int qh = 0; qh < 2; qh++){
        int qrow = qt * 128 + w * 32 + qh * 16 + mi;
        const u16* qp = base + (size_t)qrow * 1536 + hoff + quad * 8;
        qf[qh][0] = *(const short8*)(qp);
        qf[qh][1] = *(const short8*)(qp + 32);
    }
    f32x4 o[2][4];
    f32x4 lacc[2];
    #pragma unroll
    for (int qh = 0; qh < 2; qh++){
        #pragma unroll
        for (int nb = 0; nb < 4; nb++) o[qh][nb] = (f32x4){0.f, 0.f, 0.f, 0.f};
        lacc[qh] = (f32x4){0.f, 0.f, 0.f, 0.f};
    }
    int kkey = t >> 2, kseg = t & 3;
    const u16* kgp = base + (size_t)kkey * 1536 + 512 + hoff + kseg * 16;
    int vkey = lane, vdg = w;
    const u16* vgp = base + (size_t)vkey * 1536 + 1024 + hoff + vdg * 16;

    uint4 kv0 = *(const uint4*)(kgp);
    uint4 kv1 = *(const uint4*)(kgp + 8);
    uint4 vv0 = *(const uint4*)(vgp);
    uint4 vv1 = *(const uint4*)(vgp + 8);

    for (int kt = 0; kt < 16; kt++){
        __syncthreads();
        *(uint4*)&Ks[kkey * LDK + kseg * 16]     = kv0;
        *(uint4*)&Ks[kkey * LDK + kseg * 16 + 8] = kv1;
        u16 vtmp[16];
        *(uint4*)&vtmp[0] = vv0;
        *(uint4*)&vtmp[8] = vv1;
        #pragma unroll
        for (int i = 0; i < 16; i++)
            Vt[(vdg * 16 + i) * LDK + vkey] = vtmp[i];
        __syncthreads();
        if (kt < 15){
            size_t koff = (size_t)(kt + 1) * 64 * 1536;
            kv0 = *(const uint4*)(kgp + koff);
            kv1 = *(const uint4*)(kgp + koff + 8);
            vv0 = *(const uint4*)(vgp + koff);
            vv1 = *(const uint4*)(vgp + koff + 8);
        }
        short8 kb[4][2];
        #pragma unroll
        for (int nb = 0; nb < 4; nb++){
            kb[nb][0] = *(const short8*)&Ks[(nb * 16 + mi) * LDK + quad * 8];
            kb[nb][1] = *(const short8*)&Ks[(nb * 16 + mi) * LDK + quad * 8 + 32];
        }
        #pragma unroll
        for (int qh = 0; qh < 2; qh++){
            #pragma unroll
            for (int nb = 0; nb < 4; nb++){
                f32x4 z = (f32x4){0.f, 0.f, 0.f, 0.f};
                z = __builtin_amdgcn_mfma_f32_16x16x32_bf16(qf[qh][0], kb[nb][0], z, 0, 0, 0);
                z = __builtin_amdgcn_mfma_f32_16x16x32_bf16(qf[qh][1], kb[nb][1], z, 0, 0, 0);
                float e0 = exp2f(fmaf(z[0], C1_LOG2E, -C2_LOG2E));
                float e1 = exp2f(fmaf(z[1], C1_LOG2E, -C2_LOG2E));
                float e2 = exp2f(fmaf(z[2], C1_LOG2E, -C2_LOG2E));
                float e3 = exp2f(fmaf(z[3], C1_LOG2E, -C2_LOG2E));
                u32 p01 = cvt_pk_bf16(e0, e1);
                u32 p23 = cvt_pk_bf16(e2, e3);
                u16* pp = &Ps[w][(qh * 16 + quad * 4) * LDK + nb * 16 + mi];
                pp[0]       = (u16)p01;
                pp[LDK]     = (u16)(p01 >> 16);
                pp[2 * LDK] = (u16)p23;
                pp[3 * LDK] = (u16)(p23 >> 16);
            }
        }
        short8 vb[4][2], lb[2];
        #pragma unroll
        for (int nb = 0; nb < 4; nb++){
            vb[nb][0] = *(const short8*)&Vt[(nb * 16 + mi) * LDK + quad * 8];
            vb[nb][1] = *(const short8*)&Vt[(nb * 16 + mi) * LDK + quad * 8 + 32];
        }
        lb[0] = *(const short8*)&Vt[(64 + mi) * LDK + quad * 8];
        lb[1] = *(const short8*)&Vt[(64 + mi) * LDK + quad * 8 + 32];
        #pragma unroll
        for (int qh = 0; qh < 2; qh++){
            const short8 a0 = *(const short8*)&Ps[w][(qh * 16 + mi) * LDK + quad * 8];
            const short8 a1 = *(const short8*)&Ps[w][(qh * 16 + mi) * LDK + quad * 8 + 32];
            #pragma unroll
            for (int nb = 0; nb < 4; nb++){
                o[qh][nb] = __builtin_amdgcn_mfma_f32_16x16x32_bf16(a0, vb[nb][0], o[qh][nb], 0, 0, 0);
                o[qh][nb] = __builtin_amdgcn_mfma_f32_16x16x32_bf16(a1, vb[nb][1], o[qh][nb], 0, 0, 0);
            }
            lacc[qh] = __builtin_amdgcn_mfma_f32_16x16x32_bf16(a0, lb[0], lacc[qh], 0, 0, 0);
            lacc[qh] = __builtin_amdgcn_mfma_f32_16x16x32_bf16(a1, lb[1], lacc[qh], 0, 0, 0);
        }
    }
    #pragma unroll
    for (int qh = 0; qh < 2; qh++){
        float invl[4];
        #pragma unroll
        for (int r = 0; r < 4; r++) invl[r] = 1.f / lacc[qh][r];
        u16* op = out + ((size_t)b * 1024 + qt * 128 + w * 32 + qh * 16) * 512 + hoff;
        #pragma unroll
        for (int nb = 0; nb < 4; nb++){
            u32 c01 = cvt_pk_bf16(o[qh][nb][0] * invl[0], o[qh][nb][1] * invl[1]);
            u32 c23 = cvt_pk_bf16(o[qh][nb][2] * invl[2], o[qh][nb][3] * invl[3]);
            u16* cp = op + (size_t)(quad * 4) * 512 + nb * 16 + mi;
            cp[0]       = (u16)c01;
            cp[512]     = (u16)(c01 >> 16);
            cp[2 * 512] = (u16)c23;
            cp[3 * 512] = (u16)(c23 >> 16);
        }
    }
}

// ---------------- host launch ----------------
extern "C" void kernel_launch(void* const* d_in, const int* in_sizes, int n_in,
                              void* d_out, int out_size, void* d_ws, size_t ws_size,
                              hipStream_t stream){
    const float* x_in  = (const float*)d_in[0];
    const float* ln1_s = (const float*)d_in[1];
    const float* ln1_b = (const float*)d_in[2];
    const float* w_qkv = (const float*)d_in[3];
    const float* w_out = (const float*)d_in[4];
    const float* b_out = (const float*)d_in[5];
    const float* ln2_s = (const float*)d_in[6];
    const float* ln2_b = (const float*)d_in[7];
    const float* w1    = (const float*)d_in[8];
    const float* b1    = (const float*)d_in[9];
    const float* w2    = (const float*)d_in[10];
    const float* b2    = (const float*)d_in[11];
    float* out = (float*)d_out;

    char* ws = (char*)d_ws;
    float* x_f32 = (float*)ws;   ws += (size_t)M_TOK * DIMM * 4;      // 16 MB fp32 residual
    u16* bufA    = (u16*)ws;     ws += (size_t)M_TOK * DIMM * 2;      // 8 MB  (ln_out / attn_out)
    u16* bufB    = (u16*)ws;     ws += (size_t)M_TOK * MLPD * 2;      // 32 MB (qkv / mlp_h)

    size_t per_layer_w = (size_t)(1536 + 512 + 2048 + 2048) * 512;    // u16 elems (6.3 MB)
    size_t split_bytes = (size_t)2 * OSPLIT * 4 + (size_t)2 * LSPLIT * 4;  // 34.1 MB
    size_t base_used = (size_t)(ws - (char*)d_ws);

    bool split_ok = ws_size >= base_used + split_bytes + per_layer_w * 2;
    float* Opart = (float*)ws;
    float* lpart = (float*)(ws + (size_t)2 * OSPLIT * 4);
    u16* wbase = split_ok ? (u16*)(ws + split_bytes) : (u16*)ws;
    size_t wb_off = (size_t)((char*)wbase - (char*)d_ws);
    bool big = ws_size >= wb_off + per_layer_w * 2 * DEPTH;

    u16* ln_out   = bufA;
    u16* attn_out = bufA;
    u16* qkv      = bufB;
    u16* mlp_h    = bufB;

    size_t x_bytes = (size_t)M_TOK * DIMM * sizeof(float);
    hipMemcpyAsync(x_f32, x_in, x_bytes, hipMemcpyDeviceToDevice, stream);

    const size_t off_qkv = 0;
    const size_t off_out = (size_t)1536 * 512;
    const size_t off_w1  = off_out + (size_t)512 * 512;
    const size_t off_w2  = off_w1 + (size_t)2048 * 512;

    if (big){
        k_transpose_cvt<<<dim3(48, 16, 6), dim3(32, 8), 0, stream>>>(w_qkv, wbase + off_qkv * DEPTH, 512, 1536);
        k_transpose_cvt<<<dim3(16, 16, 6), dim3(32, 8), 0, stream>>>(w_out, wbase + off_out * DEPTH, 512, 512);
        k_transpose_cvt<<<dim3(64, 16, 6), dim3(32, 8), 0, stream>>>(w1,    wbase + off_w1  * DEPTH, 512, 2048);
        k_transpose_cvt<<<dim3(16, 64, 6), dim3(32, 8), 0, stream>>>(w2,    wbase + off_w2  * DEPTH, 2048, 512);
    }

    for (int i = 0; i < DEPTH; i++){
        u16 *wqkvT, *woutT, *w1T, *w2T;
        if (big){
            wqkvT = wbase + off_qkv * DEPTH + (size_t)i * 1536 * 512;
            woutT = wbase + off_out * DEPTH + (size_t)i * 512 * 512;
            w1T   = wbase + off_w1  * DEPTH + (size_t)i * 2048 * 512;
            w2T   = wbase + off_w2  * DEPTH + (size_t)i * 512 * 2048;
        } else {
            wqkvT = wbase + off_qkv; woutT = wbase + off_out;
            w1T   = wbase + off_w1;  w2T   = wbase + off_w2;
            k_transpose_cvt<<<dim3(48, 16), dim3(32, 8), 0, stream>>>(w_qkv + (size_t)i * 512 * 1536, wqkvT, 512, 1536);
            k_transpose_cvt<<<dim3(16, 16), dim3(32, 8), 0, stream>>>(w_out + (size_t)i * 512 * 512,  woutT, 512, 512);
            k_transpose_cvt<<<dim3(64, 16), dim3(32, 8), 0, stream>>>(w1    + (size_t)i * 512 * 2048, w1T,   512, 2048);
            k_transpose_cvt<<<dim3(16, 64), dim3(32, 8), 0, stream>>>(w2    + (size_t)i * 2048 * 512, w2T,   2048, 512);
        }

        k_layernorm<<<dim3(M_TOK / 4), dim3(256), 0, stream>>>(x_f32, ln1_s + i * 512, ln1_b + i * 512, ln_out);
        k_gemm128b<0><<<dim3(12, 64), dim3(256), 0, stream>>>(ln_out, wqkvT, nullptr, qkv,
                                                              M_TOK, 1536, 512);
        if (split_ok){
            k_flash_split<<<dim3(1024), dim3(256), 0, stream>>>(qkv, Opart, lpart);
            k_combine<<<dim3(2048), dim3(256), 0, stream>>>(Opart, lpart, attn_out);
        } else {
            k_flash<<<dim3(512), dim3(256), 0, stream>>>(qkv, attn_out);
        }
        k_gemm128_res<<<dim3(4, 64), dim3(256), 0, stream>>>(attn_out, woutT, b_out + i * 512, x_f32,
                                                             M_TOK, 512, 512);
        k_layernorm<<<dim3(M_TOK / 4), dim3(256), 0, stream>>>(x_f32, ln2_s + i * 512, ln2_b + i * 512, ln_out);
        k_gemm128b<1><<<dim3(16, 64), dim3(256), 0, stream>>>(ln_out, w1T, b1 + i * 2048, mlp_h,
                                                              M_TOK, 2048, 512);
        k_gemm128_res<<<dim3(4, 64), dim3(256), 0, stream>>>(mlp_h, w2T, b2 + i * 512, x_f32,
                                                             M_TOK, 512, 2048);
    }
    hipMemcpyAsync(out, x_f32, x_bytes, hipMemcpyDeviceToDevice, stream);
}

// Round 6
// 1092.905 us; speedup vs baseline: 1.6681x; 1.0547x over previous
//
#include <hip/hip_runtime.h>
#include <cstdint>
#include <cstddef>

#define M_TOK 8192
#define DIMM  512
#define HEADS 8
#define DH    64
#define MLPD  2048
#define DEPTH 6

typedef unsigned short u16;
typedef unsigned int   u32;
typedef __attribute__((ext_vector_type(8))) short short8;   // 8 bf16 (4 VGPRs)
typedef __attribute__((ext_vector_type(4))) float f32x4;    // 4 fp32 acc

__device__ __forceinline__ float bf2f(u16 u){ return __uint_as_float(((u32)u) << 16); }
__device__ __forceinline__ u16 f2bf(float f){
    u32 x = __float_as_uint(f);
    u32 r = x + 0x7fffu + ((x >> 16) & 1u);   // RNE
    return (u16)(r >> 16);
}
// packed f32x2 -> bf16x2 (RNE), 1 instr for 2 converts
__device__ __forceinline__ u32 cvt_pk_bf16(float a, float b){
    u32 r;
    asm("v_cvt_pk_bf16_f32 %0, %1, %2" : "=v"(r) : "v"(a), "v"(b));
    return r;
}
// async global->LDS, 16B per lane; lds dest wave-uniform base (+lane*16 implicit); global addr per-lane
__device__ __forceinline__ void async16(const u16* g, u16* l){
    __builtin_amdgcn_global_load_lds(
        (const __attribute__((address_space(1))) void*)(uintptr_t)(const void*)g,
        (__attribute__((address_space(3))) void*)(u32)(uintptr_t)(void*)l,
        16, 0, 0);
}
// XCD-grouping block swizzle: put all x-blocks sharing an A-row-panel on one XCD.
__device__ __forceinline__ void xcd_swizzle(int& bx, int& by){
    int nbx = gridDim.x, nby = gridDim.y;
    if ((nby & 7) == 0){
        int i = by * nbx + bx;
        int xcd = i & 7, j = i >> 3, ypg = nby >> 3;
        int yq = j / nbx;
        by = xcd * ypg + yq;
        bx = j - yq * nbx;
    }
}

// ---------------- weight transpose + cvt: fp32 in[R][C] -> bf16 out[C][R], z layers ----------------
__global__ void k_transpose_cvt(const float* __restrict__ in, u16* __restrict__ out, int R, int C){
    __shared__ u16 tile[32][33];
    size_t zoff = (size_t)blockIdx.z * R * C;
    in += zoff; out += zoff;
    int c0 = blockIdx.x * 32, r0 = blockIdx.y * 32;
    int tx = threadIdx.x, ty = threadIdx.y;           // (32, 8)
    #pragma unroll
    for (int i = 0; i < 32; i += 8)
        tile[ty + i][tx] = f2bf(in[(size_t)(r0 + ty + i) * C + c0 + tx]);
    __syncthreads();
    #pragma unroll
    for (int i = 0; i < 32; i += 8)
        out[(size_t)(c0 + ty + i) * R + r0 + tx] = tile[tx][ty + i];
}

// ---------------- LayerNorm: fp32 x row -> bf16 out; 4 rows/block, 1 wave/row ----------------
__global__ __launch_bounds__(256) void k_layernorm(const float* __restrict__ x,
                                                   const float* __restrict__ s,
                                                   const float* __restrict__ b,
                                                   u16* __restrict__ out){
    int row = blockIdx.x * 4 + (threadIdx.x >> 6);
    int lane = threadIdx.x & 63;
    const float* xp = x + (size_t)row * DIMM + lane * 8;
    float v[8];
    #pragma unroll
    for (int c = 0; c < 8; c++) v[c] = xp[c];
    float sum = 0.f, sq = 0.f;
    #pragma unroll
    for (int c = 0; c < 8; c++){ sum += v[c]; sq += v[c] * v[c]; }
    #pragma unroll
    for (int m = 32; m >= 1; m >>= 1){
        sum += __shfl_xor(sum, m);
        sq  += __shfl_xor(sq,  m);
    }
    float mu  = sum * (1.f / DIMM);
    float var = sq * (1.f / DIMM) - mu * mu;
    float rs  = rsqrtf(var + 1e-5f);
    u16* op = out + (size_t)row * DIMM + lane * 8;
    #pragma unroll
    for (int c = 0; c < 8; c++){
        int col = lane * 8 + c;
        op[c] = f2bf((v[c] - mu) * rs * s[col] + b[col]);
    }
}

// Abramowitz-Stegun 7.1.26 erf (abs err 1.5e-7): rcp + 5 FMA + exp2, no branches.
__device__ __forceinline__ float erf_as(float x){
    float ax = fabsf(x);
    float t  = __builtin_amdgcn_rcpf(fmaf(0.3275911f, ax, 1.f));
    float y  = fmaf(fmaf(fmaf(fmaf(1.061405429f, t, -1.453152027f), t,
                              1.421413741f), t, -0.284496736f), t, 0.254829592f) * t;
    float e  = exp2f(-ax * ax * 1.4426950408889634f);
    float r  = 1.f - y * e;
    return copysignf(r, x);
}
__device__ __forceinline__ float gelu_exact(float v){
    return 0.5f * v * (1.f + erf_as(v * 0.70710678118654752f));
}

#define LDT64 72   // padded stride for epilogue LDS scratch only

// ============ 128x128-tile GEMM, BK=64, dbuf + counted-vmcnt raw-barrier pipeline + T2 swizzle ========
// LDS: LINEAR [128][64] u16, 2 buffers. Chunk swizzle (16B chunks): LDS phys chunk p of row r holds
// logical chunk p ^ (r&7). Achieved by pre-swizzling the per-lane GLOBAL source (gload_lds dest stays
// linear) and XOR-ing the read offset — both sides, same involution (guide rule #21, m201 pattern).
// Sync per iter: stage(t+1); s_waitcnt vmcnt(8) [tile t done, t+1 in flight]; s_barrier; compute;
// s_barrier [all reads of buf done -> next iter may overwrite]. No vmcnt(0) drain in the loop.
// MODE 0: Cout=bf16(acc); MODE 1: Cout=bf16(gelu(acc+bias)).
template<int MODE>
__global__ __launch_bounds__(256) void k_gemm128b(const u16* __restrict__ A,
                                                  const u16* __restrict__ Bt,
                                                  const float* __restrict__ bias,
                                                  u16* __restrict__ Cout,
                                                  int M, int N, int K){
    __shared__ u16 As[2][128 * 64];
    __shared__ u16 Bs[2][128 * 64];
    int bx = blockIdx.x, by = blockIdx.y;
    xcd_swizzle(bx, by);
    int m0 = by * 128, n0 = bx * 128;
    int t = threadIdx.x;
    int w = t >> 6, lane = t & 63;
    int mi = lane & 15, quad = lane >> 4;
    int wr = w >> 1, wc = w & 1;
    int sw = mi & 7;                      // read-side XOR key (row&7 == mi&7 for fragment rows)

    // staging: wave w stages rows w*32..+31; lane covers (row=grow, chunk=lane&7);
    // source chunk pre-swizzled: cl = (lane&7) ^ grow  (row&7 == grow for all async16 batches)
    int grow = lane >> 3;
    int gcol = (((lane & 7) ^ grow) & 7) * 8;
    const u16* agl = A  + (size_t)(m0 + w * 32 + grow) * K + gcol;
    const u16* bgl = Bt + (size_t)(n0 + w * 32 + grow) * K + gcol;

    f32x4 acc[4][4];
    #pragma unroll
    for (int mt = 0; mt < 4; mt++)
        #pragma unroll
        for (int nt = 0; nt < 4; nt++) acc[mt][nt] = (f32x4){0.f, 0.f, 0.f, 0.f};

    int nt_k = K >> 6;
    {   // prologue: stage tile 0 -> buf 0 (8 loads/wave in flight)
        u16* asl = &As[0][(w * 32) * 64];
        u16* bsl = &Bs[0][(w * 32) * 64];
        #pragma unroll
        for (int i = 0; i < 4; i++){
            async16(agl + (size_t)(i * 8) * K, asl + i * 8 * 64);
            async16(bgl + (size_t)(i * 8) * K, bsl + i * 8 * 64);
        }
    }

    for (int td = 0; td < nt_k; td++){
        int cur = td & 1;
        if (td + 1 < nt_k){                    // stage next tile, then wait ONLY for tile td
            int k0 = (td + 1) << 6;
            u16* asl = &As[cur ^ 1][(w * 32) * 64];
            u16* bsl = &Bs[cur ^ 1][(w * 32) * 64];
            #pragma unroll
            for (int i = 0; i < 4; i++){
                async16(agl + (size_t)(i * 8) * K + k0, asl + i * 8 * 64);
                async16(bgl + (size_t)(i * 8) * K + k0, bsl + i * 8 * 64);
            }
            asm volatile("s_waitcnt vmcnt(8)" ::: "memory");
        } else {
            asm volatile("s_waitcnt vmcnt(0)" ::: "memory");
        }
        __builtin_amdgcn_s_barrier();          // all waves' tile-td loads landed
        __builtin_amdgcn_sched_barrier(0);
        const u16* Ab = &As[cur][0];
        const u16* Bb = &Bs[cur][0];
        #pragma unroll
        for (int kk = 0; kk < 64; kk += 32){
            const int kc = kk >> 3;            // logical chunk base: 0 or 4
            short8 af[4], bf[4];
            #pragma unroll
            for (int mt = 0; mt < 4; mt++)
                af[mt] = *(const short8*)&Ab[(wr * 64 + mt * 16 + mi) * 64 + (((quad + kc) ^ sw) * 8)];
            #pragma unroll
            for (int nt = 0; nt < 4; nt++)
                bf[nt] = *(const short8*)&Bb[(wc * 64 + nt * 16 + mi) * 64 + (((quad + kc) ^ sw) * 8)];
            #pragma unroll
            for (int mt = 0; mt < 4; mt++)
                #pragma unroll
                for (int nt = 0; nt < 4; nt++)
                    acc[mt][nt] = __builtin_amdgcn_mfma_f32_16x16x32_bf16(af[mt], bf[nt], acc[mt][nt], 0, 0, 0);
        }
        __builtin_amdgcn_sched_barrier(0);
        __builtin_amdgcn_s_barrier();          // all reads of buf[cur] done -> safe to overwrite next iter
    }

    // ---- coalesced epilogue: per-wave C-subtile through LDS (wave-private scratch over As) ----
    float bv[4];
    if (MODE == 1){
        #pragma unroll
        for (int nt = 0; nt < 4; nt++) bv[nt] = bias[n0 + wc * 64 + nt * 16 + mi];
    }
    u16* cs = ((u16*)As) + w * 16 * LDT64;     // 16x72 u16 per wave
    int erow = lane >> 2, ecol = (lane & 3) * 16;
    #pragma unroll
    for (int mt = 0; mt < 4; mt++){
        #pragma unroll
        for (int nt = 0; nt < 4; nt++)
            #pragma unroll
            for (int r = 0; r < 4; r++){
                float v = acc[mt][nt][r];
                if (MODE == 1) v = gelu_exact(v + bv[nt]);
                cs[(quad * 4 + r) * LDT64 + nt * 16 + mi] = f2bf(v);
            }
        // wave-internal write->read (DS ops in-order within a wave; compiler waits lgkmcnt)
        uint4 c0 = *(const uint4*)&cs[erow * LDT64 + ecol];
        uint4 c1 = *(const uint4*)&cs[erow * LDT64 + ecol + 8];
        u16* cp = Cout + (size_t)(m0 + wr * 64 + mt * 16 + erow) * N + n0 + wc * 64 + ecol;
        *(uint4*)cp       = c0;
        *(uint4*)(cp + 8) = c1;
    }
}

// ============ 128x128-tile GEMM, same pipeline+swizzle, fp32 residual RMW epilogue ============
__global__ __launch_bounds__(256) void k_gemm128_res(const u16* __restrict__ A,
                                                     const u16* __restrict__ Bt,
                                                     const float* __restrict__ bias,
                                                     float* __restrict__ xres,
                                                     int M, int N, int K){
    __shared__ u16 As[2][128 * 64];
    __shared__ u16 Bs[2][128 * 64];
    int bx = blockIdx.x, by = blockIdx.y;
    xcd_swizzle(bx, by);
    int m0 = by * 128, n0 = bx * 128;
    int t = threadIdx.x;
    int w = t >> 6, lane = t & 63;
    int mi = lane & 15, quad = lane >> 4;
    int wr = w >> 1, wc = w & 1;
    int sw = mi & 7;

    int grow = lane >> 3;
    int gcol = (((lane & 7) ^ grow) & 7) * 8;
    const u16* agl = A  + (size_t)(m0 + w * 32 + grow) * K + gcol;
    const u16* bgl = Bt + (size_t)(n0 + w * 32 + grow) * K + gcol;

    f32x4 acc[4][4];
    #pragma unroll
    for (int mt = 0; mt < 4; mt++)
        #pragma unroll
        for (int nt = 0; nt < 4; nt++) acc[mt][nt] = (f32x4){0.f, 0.f, 0.f, 0.f};

    int nt_k = K >> 6;
    {   // prologue
        u16* asl = &As[0][(w * 32) * 64];
        u16* bsl = &Bs[0][(w * 32) * 64];
        #pragma unroll
        for (int i = 0; i < 4; i++){
            async16(agl + (size_t)(i * 8) * K, asl + i * 8 * 64);
            async16(bgl + (size_t)(i * 8) * K, bsl + i * 8 * 64);
        }
    }

    for (int td = 0; td < nt_k; td++){
        int cur = td & 1;
        if (td + 1 < nt_k){
            int k0 = (td + 1) << 6;
            u16* asl = &As[cur ^ 1][(w * 32) * 64];
            u16* bsl = &Bs[cur ^ 1][(w * 32) * 64];
            #pragma unroll
            for (int i = 0; i < 4; i++){
                async16(agl + (size_t)(i * 8) * K + k0, asl + i * 8 * 64);
                async16(bgl + (size_t)(i * 8) * K + k0, bsl + i * 8 * 64);
            }
            asm volatile("s_waitcnt vmcnt(8)" ::: "memory");
        } else {
            asm volatile("s_waitcnt vmcnt(0)" ::: "memory");
        }
        __builtin_amdgcn_s_barrier();
        __builtin_amdgcn_sched_barrier(0);
        const u16* Ab = &As[cur][0];
        const u16* Bb = &Bs[cur][0];
        #pragma unroll
        for (int kk = 0; kk < 64; kk += 32){
            const int kc = kk >> 3;
            short8 af[4], bf[4];
            #pragma unroll
            for (int mt = 0; mt < 4; mt++)
                af[mt] = *(const short8*)&Ab[(wr * 64 + mt * 16 + mi) * 64 + (((quad + kc) ^ sw) * 8)];
            #pragma unroll
            for (int nt = 0; nt < 4; nt++)
                bf[nt] = *(const short8*)&Bb[(wc * 64 + nt * 16 + mi) * 64 + (((quad + kc) ^ sw) * 8)];
            #pragma unroll
            for (int mt = 0; mt < 4; mt++)
                #pragma unroll
                for (int nt = 0; nt < 4; nt++)
                    acc[mt][nt] = __builtin_amdgcn_mfma_f32_16x16x32_bf16(af[mt], bf[nt], acc[mt][nt], 0, 0, 0);
        }
        __builtin_amdgcn_sched_barrier(0);
        __builtin_amdgcn_s_barrier();
    }

    // ---- coalesced fp32 RMW epilogue through LDS (per-wave 16x72 fp32 region over As) ----
    float bv[4];
    #pragma unroll
    for (int nt = 0; nt < 4; nt++) bv[nt] = bias[n0 + wc * 64 + nt * 16 + mi];
    float* cs = ((float*)As) + w * 16 * LDT64;
    int erow = lane >> 2, ecol = (lane & 3) * 16;
    #pragma unroll
    for (int mt = 0; mt < 4; mt++){
        #pragma unroll
        for (int nt = 0; nt < 4; nt++)
            #pragma unroll
            for (int r = 0; r < 4; r++)
                cs[(quad * 4 + r) * LDT64 + nt * 16 + mi] = acc[mt][nt][r] + bv[nt];
        // wave-internal write->read; DS in-order within wave
        float* xp = xres + (size_t)(m0 + wr * 64 + mt * 16 + erow) * N + n0 + wc * 64 + ecol;
        #pragma unroll
        for (int j = 0; j < 4; j++){
            float4 cv = *(const float4*)&cs[erow * LDT64 + ecol + j * 4];
            float4 xv = *(const float4*)(xp + j * 4);
            xv.x += cv.x; xv.y += cv.y; xv.z += cv.z; xv.w += cv.w;
            *(float4*)(xp + j * 4) = xv;
        }
    }
}

// ---------------- MFMA flash attention ----------------
#define LDK 72
#define C1_LOG2E 0.18033688011112042f   // 0.125 * log2(e)
#define C2_LOG2E 11.541560327111707f    // 8 * log2(e)
#define OSPLIT (M_TOK * 512)            // floats per split O buffer
#define LSPLIT (M_TOK * 8)              // floats per split l buffer

// split-K flash: grid 1024 (2 splits x 512); fixed-max softmax => partials combine exactly.
__global__ __launch_bounds__(256) void k_flash_split(const u16* __restrict__ qkv,
                                                     float* __restrict__ Opart,
                                                     float* __restrict__ lpart){
    __shared__ u16 Ks[64 * LDK];        // [key][dim]
    __shared__ u16 Vt[80 * LDK];        // [dim][key]; rows 64..79 = 1.0 (l-accumulator)
    __shared__ u16 Ps[4][32 * LDK];     // per-wave P [q32][key]
    // XCD swizzle: nwg=1024, cpx=128 -> XCD k owns batch k (both splits co-located)
    int wg = (blockIdx.x & 7) * 128 + (blockIdx.x >> 3);
    int qt = wg & 7, h = (wg >> 3) & 7, sp = (wg >> 6) & 1, b = wg >> 7;
    int t = threadIdx.x;
    int w = t >> 6, lane = t & 63;
    int mi = lane & 15, quad = lane >> 4;

    for (int i = t; i < 16 * 64; i += 256){
        int d = i >> 6, kk = i & 63;
        Vt[(64 + d) * LDK + kk] = 0x3F80;   // bf16 1.0
    }

    const u16* base = qkv + ((size_t)b * 1024) * 1536;
    int hoff = h * 64;

    short8 qf[2][2];
    #pragma unroll
    for (int qh = 0; qh < 2; qh++){
        int qrow = qt * 128 + w * 32 + qh * 16 + mi;
        const u16* qp = base + (size_t)qrow * 1536 + hoff + quad * 8;
        qf[qh][0] = *(const short8*)(qp);
        qf[qh][1] = *(const short8*)(qp + 32);
    }

    f32x4 o[2][4];
    f32x4 lacc[2];
    #pragma unroll
    for (int qh = 0; qh < 2; qh++){
        #pragma unroll
        for (int nb = 0; nb < 4; nb++) o[qh][nb] = (f32x4){0.f, 0.f, 0.f, 0.f};
        lacc[qh] = (f32x4){0.f, 0.f, 0.f, 0.f};
    }

    int kkey = t >> 2, kseg = t & 3;
    const u16* kgp = base + (size_t)kkey * 1536 + 512 + hoff + kseg * 16;
    int vkey = lane, vdg = w;
    const u16* vgp = base + (size_t)vkey * 1536 + 1024 + hoff + vdg * 16;

    int kt0 = sp * 8;
    size_t koff0 = (size_t)kt0 * 64 * 1536;
    uint4 kv0 = *(const uint4*)(kgp + koff0);
    uint4 kv1 = *(const uint4*)(kgp + koff0 + 8);
    uint4 vv0 = *(const uint4*)(vgp + koff0);
    uint4 vv1 = *(const uint4*)(vgp + koff0 + 8);

    for (int kt = kt0; kt < kt0 + 8; kt++){
        __syncthreads();                              // prev tile's LDS reads done
        *(uint4*)&Ks[kkey * LDK + kseg * 16]     = kv0;
        *(uint4*)&Ks[kkey * LDK + kseg * 16 + 8] = kv1;
        u16 vtmp[16];
        *(uint4*)&vtmp[0] = vv0;
        *(uint4*)&vtmp[8] = vv1;
        #pragma unroll
        for (int i = 0; i < 16; i++)
            Vt[(vdg * 16 + i) * LDK + vkey] = vtmp[i];   // 2 lanes/bank = free
        __syncthreads();

        if (kt < kt0 + 7){                            // issue next tile's loads under MFMA
            size_t koff = (size_t)(kt + 1) * 64 * 1536;
            kv0 = *(const uint4*)(kgp + koff);
            kv1 = *(const uint4*)(kgp + koff + 8);
            vv0 = *(const uint4*)(vgp + koff);
            vv1 = *(const uint4*)(vgp + koff + 8);
        }

        short8 kb[4][2];
        #pragma unroll
        for (int nb = 0; nb < 4; nb++){
            kb[nb][0] = *(const short8*)&Ks[(nb * 16 + mi) * LDK + quad * 8];
            kb[nb][1] = *(const short8*)&Ks[(nb * 16 + mi) * LDK + quad * 8 + 32];
        }
        #pragma unroll
        for (int qh = 0; qh < 2; qh++){
            #pragma unroll
            for (int nb = 0; nb < 4; nb++){
                f32x4 z = (f32x4){0.f, 0.f, 0.f, 0.f};
                z = __builtin_amdgcn_mfma_f32_16x16x32_bf16(qf[qh][0], kb[nb][0], z, 0, 0, 0);
                z = __builtin_amdgcn_mfma_f32_16x16x32_bf16(qf[qh][1], kb[nb][1], z, 0, 0, 0);
                float e0 = exp2f(fmaf(z[0], C1_LOG2E, -C2_LOG2E));
                float e1 = exp2f(fmaf(z[1], C1_LOG2E, -C2_LOG2E));
                float e2 = exp2f(fmaf(z[2], C1_LOG2E, -C2_LOG2E));
                float e3 = exp2f(fmaf(z[3], C1_LOG2E, -C2_LOG2E));
                u32 p01 = cvt_pk_bf16(e0, e1);
                u32 p23 = cvt_pk_bf16(e2, e3);
                u16* pp = &Ps[w][(qh * 16 + quad * 4) * LDK + nb * 16 + mi];
                pp[0]       = (u16)p01;
                pp[LDK]     = (u16)(p01 >> 16);
                pp[2 * LDK] = (u16)p23;
                pp[3 * LDK] = (u16)(p23 >> 16);
            }
        }
        short8 vb[4][2], lb[2];
        #pragma unroll
        for (int nb = 0; nb < 4; nb++){
            vb[nb][0] = *(const short8*)&Vt[(nb * 16 + mi) * LDK + quad * 8];
            vb[nb][1] = *(const short8*)&Vt[(nb * 16 + mi) * LDK + quad * 8 + 32];
        }
        lb[0] = *(const short8*)&Vt[(64 + mi) * LDK + quad * 8];
        lb[1] = *(const short8*)&Vt[(64 + mi) * LDK + quad * 8 + 32];
        #pragma unroll
        for (int qh = 0; qh < 2; qh++){
            const short8 a0 = *(const short8*)&Ps[w][(qh * 16 + mi) * LDK + quad * 8];
            const short8 a1 = *(const short8*)&Ps[w][(qh * 16 + mi) * LDK + quad * 8 + 32];
            #pragma unroll
            for (int nb = 0; nb < 4; nb++){
                o[qh][nb] = __builtin_amdgcn_mfma_f32_16x16x32_bf16(a0, vb[nb][0], o[qh][nb], 0, 0, 0);
                o[qh][nb] = __builtin_amdgcn_mfma_f32_16x16x32_bf16(a1, vb[nb][1], o[qh][nb], 0, 0, 0);
            }
            lacc[qh] = __builtin_amdgcn_mfma_f32_16x16x32_bf16(a0, lb[0], lacc[qh], 0, 0, 0);
            lacc[qh] = __builtin_amdgcn_mfma_f32_16x16x32_bf16(a1, lb[1], lacc[qh], 0, 0, 0);
        }
    }
    float* Ob = Opart + (size_t)sp * OSPLIT;
    float* lb2 = lpart + (size_t)sp * LSPLIT;
    #pragma unroll
    for (int qh = 0; qh < 2; qh++){
        int grow0 = b * 1024 + qt * 128 + w * 32 + qh * 16;
        float* op = Ob + (size_t)grow0 * 512 + hoff;
        #pragma unroll
        for (int nb = 0; nb < 4; nb++)
            #pragma unroll
            for (int r = 0; r < 4; r++)
                op[(size_t)(quad * 4 + r) * 512 + nb * 16 + mi] = o[qh][nb][r];
        if (mi == 0){
            #pragma unroll
            for (int r = 0; r < 4; r++)
                lb2[(size_t)(grow0 + quad * 4 + r) * 8 + h] = lacc[qh][r];
        }
    }
}

// combine: out = bf16((O0+O1)/(l0+l1)); 8 elems/thread, fully coalesced
__global__ __launch_bounds__(256) void k_combine(const float* __restrict__ Opart,
                                                 const float* __restrict__ lpart,
                                                 u16* __restrict__ out){
    int tid = blockIdx.x * 256 + threadIdx.x;
    size_t basei = (size_t)tid * 8;
    int row = (int)(basei >> 9), col = (int)(basei & 511), h = col >> 6;
    float l = lpart[(size_t)row * 8 + h] + lpart[(size_t)LSPLIT + (size_t)row * 8 + h];
    float inv = 1.f / l;
    float4 a0 = *(const float4*)(Opart + basei);
    float4 a1 = *(const float4*)(Opart + basei + 4);
    float4 b0 = *(const float4*)(Opart + (size_t)OSPLIT + basei);
    float4 b1 = *(const float4*)(Opart + (size_t)OSPLIT + basei + 4);
    uint4 r;
    r.x = cvt_pk_bf16((a0.x + b0.x) * inv, (a0.y + b0.y) * inv);
    r.y = cvt_pk_bf16((a0.z + b0.z) * inv, (a0.w + b0.w) * inv);
    r.z = cvt_pk_bf16((a1.x + b1.x) * inv, (a1.y + b1.y) * inv);
    r.w = cvt_pk_bf16((a1.z + b1.z) * inv, (a1.w + b1.w) * inv);
    *(uint4*)(out + basei) = r;
}

// fallback single-pass flash, used when workspace too small for partials
__global__ __launch_bounds__(256) void k_flash(const u16* __restrict__ qkv, u16* __restrict__ out){
    __shared__ u16 Ks[64 * LDK];
    __shared__ u16 Vt[80 * LDK];
    __shared__ u16 Ps[4][32 * LDK];
    int wg = (blockIdx.x & 7) * 64 + (blockIdx.x >> 3);
    int qt = wg & 7, h = (wg >> 3) & 7, b = wg >> 6;
    int t = threadIdx.x;
    int w = t >> 6, lane = t & 63;
    int mi = lane & 15, quad = lane >> 4;

    for (int i = t; i < 16 * 64; i += 256){
        int d = i >> 6, kk = i & 63;
        Vt[(64 + d) * LDK + kk] = 0x3F80;
    }
    const u16* base = qkv + ((size_t)b * 1024) * 1536;
    int hoff = h * 64;

    short8 qf[2][2];
    #pragma unroll
    for (int qh = 0; qh < 2; qh++){
        int qrow = qt * 128 + w * 32 + qh * 16 + mi;
        const u16* qp = base + (size_t)qrow * 1536 + hoff + quad * 8;
        qf[qh][0] = *(const short8*)(qp);
        qf[qh][1] = *(const short8*)(qp + 32);
    }
    f32x4 o[2][4];
    f32x4 lacc[2];
    #pragma unroll
    for (int qh = 0; qh < 2; qh++){
        #pragma unroll
        for (int nb = 0; nb < 4; nb++) o[qh][nb] = (f32x4){0.f, 0.f, 0.f, 0.f};
        lacc[qh] = (f32x4){0.f, 0.f, 0.f, 0.f};
    }
    int kkey = t >> 2, kseg = t & 3;
    const u16* kgp = base + (size_t)kkey * 1536 + 512 + hoff + kseg * 16;
    int vkey = lane, vdg = w;
    const u16* vgp = base + (size_t)vkey * 1536 + 1024 + hoff + vdg * 16;

    uint4 kv0 = *(const uint4*)(kgp);
    uint4 kv1 = *(const uint4*)(kgp + 8);
    uint4 vv0 = *(const uint4*)(vgp);
    uint4 vv1 = *(const uint4*)(vgp + 8);

    for (int kt = 0; kt < 16; kt++){
        __syncthreads();
        *(uint4*)&Ks[kkey * LDK + kseg * 16]     = kv0;
        *(uint4*)&Ks[kkey * LDK + kseg * 16 + 8] = kv1;
        u16 vtmp[16];
        *(uint4*)&vtmp[0] = vv0;
        *(uint4*)&vtmp[8] = vv1;
        #pragma unroll
        for (int i = 0; i < 16; i++)
            Vt[(vdg * 16 + i) * LDK + vkey] = vtmp[i];
        __syncthreads();
        if (kt < 15){
            size_t koff = (size_t)(kt + 1) * 64 * 1536;
            kv0 = *(const uint4*)(kgp + koff);
            kv1 = *(const uint4*)(kgp + koff + 8);
            vv0 = *(const uint4*)(vgp + koff);
            vv1 = *(const uint4*)(vgp + koff + 8);
        }
        short8 kb[4][2];
        #pragma unroll
        for (int nb = 0; nb < 4; nb++){
            kb[nb][0] = *(const short8*)&Ks[(nb * 16 + mi) * LDK + quad * 8];
            kb[nb][1] = *(const short8*)&Ks[(nb * 16 + mi) * LDK + quad * 8 + 32];
        }
        #pragma unroll
        for (int qh = 0; qh < 2; qh++){
            #pragma unroll
            for (int nb = 0; nb < 4; nb++){
                f32x4 z = (f32x4){0.f, 0.f, 0.f, 0.f};
                z = __builtin_amdgcn_mfma_f32_16x16x32_bf16(qf[qh][0], kb[nb][0], z, 0, 0, 0);
                z = __builtin_amdgcn_mfma_f32_16x16x32_bf16(qf[qh][1], kb[nb][1], z, 0, 0, 0);
                float e0 = exp2f(fmaf(z[0], C1_LOG2E, -C2_LOG2E));
                float e1 = exp2f(fmaf(z[1], C1_LOG2E, -C2_LOG2E));
                float e2 = exp2f(fmaf(z[2], C1_LOG2E, -C2_LOG2E));
                float e3 = exp2f(fmaf(z[3], C1_LOG2E, -C2_LOG2E));
                u32 p01 = cvt_pk_bf16(e0, e1);
                u32 p23 = cvt_pk_bf16(e2, e3);
                u16* pp = &Ps[w][(qh * 16 + quad * 4) * LDK + nb * 16 + mi];
                pp[0]       = (u16)p01;
                pp[LDK]     = (u16)(p01 >> 16);
                pp[2 * LDK] = (u16)p23;
                pp[3 * LDK] = (u16)(p23 >> 16);
            }
        }
        short8 vb[4][2], lb[2];
        #pragma unroll
        for (int nb = 0; nb < 4; nb++){
            vb[nb][0] = *(const short8*)&Vt[(nb * 16 + mi) * LDK + quad * 8];
            vb[nb][1] = *(const short8*)&Vt[(nb * 16 + mi) * LDK + quad * 8 + 32];
        }
        lb[0] = *(const short8*)&Vt[(64 + mi) * LDK + quad * 8];
        lb[1] = *(const short8*)&Vt[(64 + mi) * LDK + quad * 8 + 32];
        #pragma unroll
        for (int qh = 0; qh < 2; qh++){
            const short8 a0 = *(const short8*)&Ps[w][(qh * 16 + mi) * LDK + quad * 8];
            const short8 a1 = *(const short8*)&Ps[w][(qh * 16 + mi) * LDK + quad * 8 + 32];
            #pragma unroll
            for (int nb = 0; nb < 4; nb++){
                o[qh][nb] = __builtin_amdgcn_mfma_f32_16x16x32_bf16(a0, vb[nb][0], o[qh][nb], 0, 0, 0);
                o[qh][nb] = __builtin_amdgcn_mfma_f32_16x16x32_bf16(a1, vb[nb][1], o[qh][nb], 0, 0, 0);
            }
            lacc[qh] = __builtin_amdgcn_mfma_f32_16x16x32_bf16(a0, lb[0], lacc[qh], 0, 0, 0);
            lacc[qh] = __builtin_amdgcn_mfma_f32_16x16x32_bf16(a1, lb[1], lacc[qh], 0, 0, 0);
        }
    }
    #pragma unroll
    for (int qh = 0; qh < 2; qh++){
        float invl[4];
        #pragma unroll
        for (int r = 0; r < 4; r++) invl[r] = 1.f / lacc[qh][r];
        u16* op = out + ((size_t)b * 1024 + qt * 128 + w * 32 + qh * 16) * 512 + hoff;
        #pragma unroll
        for (int nb = 0; nb < 4; nb++){
            u32 c01 = cvt_pk_bf16(o[qh][nb][0] * invl[0], o[qh][nb][1] * invl[1]);
            u32 c23 = cvt_pk_bf16(o[qh][nb][2] * invl[2], o[qh][nb][3] * invl[3]);
            u16* cp = op + (size_t)(quad * 4) * 512 + nb * 16 + mi;
            cp[0]       = (u16)c01;
            cp[512]     = (u16)(c01 >> 16);
            cp[2 * 512] = (u16)c23;
            cp[3 * 512] = (u16)(c23 >> 16);
        }
    }
}

// ---------------- host launch ----------------
extern "C" void kernel_launch(void* const* d_in, const int* in_sizes, int n_in,
                              void* d_out, int out_size, void* d_ws, size_t ws_size,
                              hipStream_t stream){
    const float* x_in  = (const float*)d_in[0];
    const float* ln1_s = (const float*)d_in[1];
    const float* ln1_b = (const float*)d_in[2];
    const float* w_qkv = (const float*)d_in[3];
    const float* w_out = (const float*)d_in[4];
    const float* b_out = (const float*)d_in[5];
    const float* ln2_s = (const float*)d_in[6];
    const float* ln2_b = (const float*)d_in[7];
    const float* w1    = (const float*)d_in[8];
    const float* b1    = (const float*)d_in[9];
    const float* w2    = (const float*)d_in[10];
    const float* b2    = (const float*)d_in[11];
    float* out = (float*)d_out;

    char* ws = (char*)d_ws;
    float* x_f32 = (float*)ws;   ws += (size_t)M_TOK * DIMM * 4;      // 16 MB fp32 residual
    u16* bufA    = (u16*)ws;     ws += (size_t)M_TOK * DIMM * 2;      // 8 MB  (ln_out / attn_out)
    u16* bufB    = (u16*)ws;     ws += (size_t)M_TOK * MLPD * 2;      // 32 MB (qkv / mlp_h)

    size_t per_layer_w = (size_t)(1536 + 512 + 2048 + 2048) * 512;    // u16 elems (6.3 MB)
    size_t split_bytes = (size_t)2 * OSPLIT * 4 + (size_t)2 * LSPLIT * 4;  // 34.1 MB
    size_t base_used = (size_t)(ws - (char*)d_ws);

    bool split_ok = ws_size >= base_used + split_bytes + per_layer_w * 2;
    float* Opart = (float*)ws;
    float* lpart = (float*)(ws + (size_t)2 * OSPLIT * 4);
    u16* wbase = split_ok ? (u16*)(ws + split_bytes) : (u16*)ws;
    size_t wb_off = (size_t)((char*)wbase - (char*)d_ws);
    bool big = ws_size >= wb_off + per_layer_w * 2 * DEPTH;

    u16* ln_out   = bufA;
    u16* attn_out = bufA;
    u16* qkv      = bufB;
    u16* mlp_h    = bufB;

    size_t x_bytes = (size_t)M_TOK * DIMM * sizeof(float);
    hipMemcpyAsync(x_f32, x_in, x_bytes, hipMemcpyDeviceToDevice, stream);

    const size_t off_qkv = 0;
    const size_t off_out = (size_t)1536 * 512;
    const size_t off_w1  = off_out + (size_t)512 * 512;
    const size_t off_w2  = off_w1 + (size_t)2048 * 512;

    if (big){
        k_transpose_cvt<<<dim3(48, 16, 6), dim3(32, 8), 0, stream>>>(w_qkv, wbase + off_qkv * DEPTH, 512, 1536);
        k_transpose_cvt<<<dim3(16, 16, 6), dim3(32, 8), 0, stream>>>(w_out, wbase + off_out * DEPTH, 512, 512);
        k_transpose_cvt<<<dim3(64, 16, 6), dim3(32, 8), 0, stream>>>(w1,    wbase + off_w1  * DEPTH, 512, 2048);
        k_transpose_cvt<<<dim3(16, 64, 6), dim3(32, 8), 0, stream>>>(w2,    wbase + off_w2  * DEPTH, 2048, 512);
    }

    for (int i = 0; i < DEPTH; i++){
        u16 *wqkvT, *woutT, *w1T, *w2T;
        if (big){
            wqkvT = wbase + off_qkv * DEPTH + (size_t)i * 1536 * 512;
            woutT = wbase + off_out * DEPTH + (size_t)i * 512 * 512;
            w1T   = wbase + off_w1  * DEPTH + (size_t)i * 2048 * 512;
            w2T   = wbase + off_w2  * DEPTH + (size_t)i * 512 * 2048;
        } else {
            wqkvT = wbase + off_qkv; woutT = wbase + off_out;
            w1T   = wbase + off_w1;  w2T   = wbase + off_w2;
            k_transpose_cvt<<<dim3(48, 16), dim3(32, 8), 0, stream>>>(w_qkv + (size_t)i * 512 * 1536, wqkvT, 512, 1536);
            k_transpose_cvt<<<dim3(16, 16), dim3(32, 8), 0, stream>>>(w_out + (size_t)i * 512 * 512,  woutT, 512, 512);
            k_transpose_cvt<<<dim3(64, 16), dim3(32, 8), 0, stream>>>(w1    + (size_t)i * 512 * 2048, w1T,   512, 2048);
            k_transpose_cvt<<<dim3(16, 64), dim3(32, 8), 0, stream>>>(w2    + (size_t)i * 2048 * 512, w2T,   2048, 512);
        }

        k_layernorm<<<dim3(M_TOK / 4), dim3(256), 0, stream>>>(x_f32, ln1_s + i * 512, ln1_b + i * 512, ln_out);
        k_gemm128b<0><<<dim3(12, 64), dim3(256), 0, stream>>>(ln_out, wqkvT, nullptr, qkv,
                                                              M_TOK, 1536, 512);
        if (split_ok){
            k_flash_split<<<dim3(1024), dim3(256), 0, stream>>>(qkv, Opart, lpart);
            k_combine<<<dim3(2048), dim3(256), 0, stream>>>(Opart, lpart, attn_out);
        } else {
            k_flash<<<dim3(512), dim3(256), 0, stream>>>(qkv, attn_out);
        }
        k_gemm128_res<<<dim3(4, 64), dim3(256), 0, stream>>>(attn_out, woutT, b_out + i * 512, x_f32,
                                                             M_TOK, 512, 512);
        k_layernorm<<<dim3(M_TOK / 4), dim3(256), 0, stream>>>(x_f32, ln2_s + i * 512, ln2_b + i * 512, ln_out);
        k_gemm128b<1><<<dim3(16, 64), dim3(256), 0, stream>>>(ln_out, w1T, b1 + i * 2048, mlp_h,
                                                              M_TOK, 2048, 512);
        k_gemm128_res<<<dim3(4, 64), dim3(256), 0, stream>>>(mlp_h, w2T, b2 + i * 512, x_f32,
                                                             M_TOK, 512, 2048);
    }
    hipMemcpyAsync(out, x_f32, x_bytes, hipMemcpyDeviceToDevice, stream);
}